// Round 6
// baseline (259.300 us; speedup 1.0000x reference)
//
#include <hip/hip_runtime.h>
#include <cstdint>
#include <cstddef>

typedef unsigned short u16;
typedef unsigned int u32;
typedef __attribute__((ext_vector_type(8))) short short8;
typedef __attribute__((ext_vector_type(4))) float f32x4;

#define CD 256
#define HWD 4096
#define NHD 4
#define HDD 64

static __device__ __forceinline__ u16 f2b(float f) {
    u32 u = __builtin_bit_cast(u32, f);
    return (u16)((u + 0x7fffu + ((u >> 16) & 1u)) >> 16);
}
static __device__ __forceinline__ float b2f(u16 h) {
    return __builtin_bit_cast(float, (u32)h << 16);
}
static __device__ __forceinline__ u32 pk2(float a, float b) {
    return (u32)f2b(a) | ((u32)f2b(b) << 16);
}
// cheap round-half-up bf16 pack (positive values; bias cancels in softmax ratio)
static __device__ __forceinline__ u32 pk2r(float a, float b) {
    u32 ua = __builtin_bit_cast(u32, a) + 0x8000u;
    u32 ub = __builtin_bit_cast(u32, b) + 0x8000u;
    return (ua >> 16) | (ub & 0xffff0000u);
}
static __device__ __forceinline__ float fexp2(float x) {
#if __has_builtin(__builtin_amdgcn_exp2f)
    return __builtin_amdgcn_exp2f(x);
#else
    return __expf(x * 0.69314718056f);
#endif
}

// ---------------------------------------------------------------------------
// LayerNorm over C + transpose to bf16 [b][p][c].
// grid 256: bid>>7 = tensor, (bid>>6)&1 = b, (bid&63)*64 = p0. block 256.
// ---------------------------------------------------------------------------
__global__ __launch_bounds__(256) void ln_transpose(
    const float* __restrict__ x0, const float* __restrict__ x1,
    const float* __restrict__ g0, const float* __restrict__ b0,
    const float* __restrict__ g1, const float* __restrict__ b1,
    u16* __restrict__ out0, u16* __restrict__ out1)
{
    int bid = blockIdx.x;
    int t = bid >> 7, b = (bid >> 6) & 1, p0 = (bid & 63) << 6;
    const float* x = t ? x1 : x0;
    const float* g = t ? g1 : g0;
    const float* bb = t ? b1 : b0;
    u16* out = t ? out1 : out0;

    int tid = threadIdx.x;
    int tx = tid & 63, ty = tid >> 6;
    const float* xb = x + (size_t)b * CD * HWD + p0 + tx;

    __shared__ float red[2][4][64];
    __shared__ u16 T[256][65];

    float s = 0.f, sq = 0.f;
    #pragma unroll 8
    for (int i = 0; i < 64; ++i) {
        float v = xb[(size_t)(ty * 64 + i) * HWD];
        s += v; sq += v * v;
    }
    red[0][ty][tx] = s; red[1][ty][tx] = sq;
    __syncthreads();
    float st  = red[0][0][tx] + red[0][1][tx] + red[0][2][tx] + red[0][3][tx];
    float sqt = red[1][0][tx] + red[1][1][tx] + red[1][2][tx] + red[1][3][tx];
    float mean = st * (1.f / 256.f);
    float var = sqt * (1.f / 256.f) - mean * mean;
    float rstd = rsqrtf(var + 1e-5f);

    #pragma unroll 8
    for (int i = 0; i < 64; ++i) {
        int c = ty * 64 + i;
        float v = (xb[(size_t)c * HWD] - mean) * rstd * g[c] + bb[c];
        T[c][tx] = f2b(v);
    }
    __syncthreads();

    int pr = tid >> 5, c0 = (tid & 31) * 8;
    #pragma unroll
    for (int pass = 0; pass < 8; ++pass) {
        int p = pass * 8 + pr;
        u16 tmp[8];
        #pragma unroll
        for (int j = 0; j < 8; ++j) tmp[j] = T[c0 + j][p];
        *(uint4*)&out[((size_t)b * HWD + p0 + p) * CD + c0] = *(const uint4*)tmp;
    }
}

// ---------------------------------------------------------------------------
// conv1x1 GEMM, bf16 [p][c] input, register-prefetched K-loop.
// grid (2 ctiles, 32 ptiles, 6 = mm*2+b), block 256.
// ---------------------------------------------------------------------------
__global__ __launch_bounds__(256) void qkv_gemm(
    const u16* __restrict__ xT, const u16* __restrict__ gT,
    const float* __restrict__ qw1, const float* __restrict__ qb1,
    const float* __restrict__ kw1, const float* __restrict__ kb1,
    const float* __restrict__ vw1, const float* __restrict__ vb1,
    u16* __restrict__ q1, u16* __restrict__ k1, u16* __restrict__ v1)
{
    int z = blockIdx.z;
    int mm = z >> 1, b = z & 1;
    const u16* X    = (mm == 0) ? xT : gT;
    const float* W  = (mm == 0) ? qw1 : (mm == 1) ? kw1 : vw1;
    const float* Bi = (mm == 0) ? qb1 : (mm == 1) ? kb1 : vb1;
    u16* Y          = (mm == 0) ? q1 : (mm == 1) ? k1 : v1;

    int n0 = blockIdx.x * 128;
    int p0 = blockIdx.y * 128;

    __shared__ u16 As[128][40];
    __shared__ u16 Bs[128][40];

    int tid = threadIdx.x;
    int lane = tid & 63, w = tid >> 6;
    int wm = w >> 1, wn = w & 1;
    int l15 = lane & 15, quad = lane >> 4;

    f32x4 acc[4][4];
    #pragma unroll
    for (int mi = 0; mi < 4; ++mi)
        #pragma unroll
        for (int nj = 0; nj < 4; ++nj)
            acc[mi][nj] = (f32x4){0.f, 0.f, 0.f, 0.f};

    const u16* Xb = X + (size_t)b * HWD * CD;

    int arow = tid >> 1, akh = (tid & 1) * 16;
    const u16* agp = Xb + (size_t)(p0 + arow) * CD + akh;
    const float* wgp = W + (size_t)(n0 + arow) * CD + akh;

    uint4 ra0 = *(const uint4*)(agp);
    uint4 ra1 = *(const uint4*)(agp + 8);
    float4 rw0 = ((const float4*)wgp)[0], rw1 = ((const float4*)wgp)[1];
    float4 rw2 = ((const float4*)wgp)[2], rw3 = ((const float4*)wgp)[3];

    for (int kt = 0; kt < 8; ++kt) {
        __syncthreads();
        *(uint4*)&As[arow][akh] = ra0;
        *(uint4*)&As[arow][akh + 8] = ra1;
        {
            uint4 qa, qb;
            qa.x = pk2(rw0.x, rw0.y); qa.y = pk2(rw0.z, rw0.w);
            qa.z = pk2(rw1.x, rw1.y); qa.w = pk2(rw1.z, rw1.w);
            qb.x = pk2(rw2.x, rw2.y); qb.y = pk2(rw2.z, rw2.w);
            qb.z = pk2(rw3.x, rw3.y); qb.w = pk2(rw3.z, rw3.w);
            *(uint4*)&Bs[arow][akh] = qa;
            *(uint4*)&Bs[arow][akh + 8] = qb;
        }
        if (kt < 7) {
            const u16* ag2 = agp + (kt + 1) * 32;
            const float* wg2 = wgp + (kt + 1) * 32;
            ra0 = *(const uint4*)(ag2);
            ra1 = *(const uint4*)(ag2 + 8);
            rw0 = ((const float4*)wg2)[0]; rw1 = ((const float4*)wg2)[1];
            rw2 = ((const float4*)wg2)[2]; rw3 = ((const float4*)wg2)[3];
        }
        __syncthreads();

        short8 af[4], bf[4];
        #pragma unroll
        for (int mi = 0; mi < 4; ++mi)
            af[mi] = *(const short8*)&As[wm * 64 + mi * 16 + l15][quad * 8];
        #pragma unroll
        for (int nj = 0; nj < 4; ++nj)
            bf[nj] = *(const short8*)&Bs[wn * 64 + nj * 16 + l15][quad * 8];
        #pragma unroll
        for (int mi = 0; mi < 4; ++mi)
            #pragma unroll
            for (int nj = 0; nj < 4; ++nj)
                acc[mi][nj] = __builtin_amdgcn_mfma_f32_16x16x32_bf16(
                    af[mi], bf[nj], acc[mi][nj], 0, 0, 0);
    }

    u16* Yb = Y + (size_t)b * HWD * CD;
    float bias[4];
    #pragma unroll
    for (int nj = 0; nj < 4; ++nj)
        bias[nj] = Bi[n0 + wn * 64 + nj * 16 + l15];
    #pragma unroll
    for (int mi = 0; mi < 4; ++mi) {
        #pragma unroll
        for (int r = 0; r < 4; ++r) {
            int p = p0 + wm * 64 + mi * 16 + quad * 4 + r;
            #pragma unroll
            for (int nj = 0; nj < 4; ++nj) {
                int ch = n0 + wn * 64 + nj * 16 + l15;
                Yb[(size_t)p * CD + ch] = f2b(acc[mi][nj][r] + bias[nj]);
            }
        }
    }
}

// ---------------------------------------------------------------------------
// depthwise 3x3 SAME + bias; q scaled by 0.125*log2(e) (softmax in exp2 domain).
// Q,K out [b][n][c]; V out transposed [b*256+c][n].
// grid 1536, block 256 (lane = channel).
// ---------------------------------------------------------------------------
__global__ __launch_bounds__(256) void dwconv_nc(
    const u16* __restrict__ q1, const u16* __restrict__ k1, const u16* __restrict__ v1,
    const float* __restrict__ qw2, const float* __restrict__ qb2,
    const float* __restrict__ kw2, const float* __restrict__ kb2,
    const float* __restrict__ vw2, const float* __restrict__ vb2,
    u16* __restrict__ Q, u16* __restrict__ K, u16* __restrict__ Vt)
{
    int bid = blockIdx.x;
    int which = bid >> 9;
    int b = (bid >> 8) & 1;
    int p0 = (bid & 255) * 16;

    const u16* in = ((which == 0) ? q1 : (which == 1) ? k1 : v1) + (size_t)b * HWD * CD;
    const float* wsrc = (which == 0) ? qw2 : (which == 1) ? kw2 : vw2;
    const float* bsrc = (which == 0) ? qb2 : (which == 1) ? kb2 : vb2;
    float oscale = (which == 0) ? 0.18033688011112042f : 1.0f;

    int c = threadIdx.x;
    float w9[9];
    #pragma unroll
    for (int j = 0; j < 9; ++j) w9[j] = wsrc[c * 9 + j];
    float bias = bsrc[c];

    int h = p0 >> 6, w0 = p0 & 63;

    float accv[16];
    #pragma unroll
    for (int pi = 0; pi < 16; ++pi) accv[pi] = bias;

    #pragma unroll
    for (int dh = -1; dh <= 1; ++dh) {
        int hh = h + dh;
        if (hh < 0 || hh >= 64) continue;
        #pragma unroll
        for (int dw = -1; dw <= 1; ++dw) {
            float wt = w9[(dh + 1) * 3 + (dw + 1)];
            #pragma unroll
            for (int pi = 0; pi < 16; ++pi) {
                int wc = w0 + pi + dw;
                if (wc < 0 || wc >= 64) continue;
                int np = hh * 64 + wc;
                accv[pi] += wt * b2f(in[(size_t)np * CD + c]);
            }
        }
    }

    if (which == 2) {
        u32 w8[8];
        #pragma unroll
        for (int j = 0; j < 8; ++j) w8[j] = pk2(accv[2 * j], accv[2 * j + 1]);
        uint4* dst = (uint4*)(Vt + ((size_t)(b * CD + c)) * HWD + p0);
        dst[0] = make_uint4(w8[0], w8[1], w8[2], w8[3]);
        dst[1] = make_uint4(w8[4], w8[5], w8[6], w8[7]);
    } else {
        u16* out = ((which == 0) ? Q : K) + (size_t)b * HWD * CD;
        #pragma unroll
        for (int pi = 0; pi < 16; ++pi)
            out[(size_t)(p0 + pi) * CD + c] = f2b(accv[pi] * oscale);
    }
}

// ---------------------------------------------------------------------------
// Barrier-free flash attention (S^T formulation), key-split x2.
// K/V fragments loaded straight from global in MFMA layout (L1 shares them
// across the block's 4 waves). Only P round-trips LDS, in wave-private rows
// -> ZERO __syncthreads in the K-loop. Partial (unnormalized O fp32, psum)
// written to workspace; combined exactly in out_gemm (max-free softmax).
// grid (32 qtiles, 8 bh, 2 ks), block 256. LDS 18.4 KB.
// ---------------------------------------------------------------------------
__global__ __launch_bounds__(256, 2) void attn_kernel(
    const u16* __restrict__ Q, const u16* __restrict__ K,
    const u16* __restrict__ Vt, float* __restrict__ Opart,
    float* __restrict__ Psum)
{
    int qt = blockIdx.x;
    int bh = blockIdx.y;
    int ks = blockIdx.z;
    int b = bh >> 2, nh = bh & 3;

    __shared__ u16 Ps[128][72];   // [qrow][key], wave-private rows

    int tid = threadIdx.x;
    int lane = tid & 63, w = tid >> 6;
    int l15 = lane & 15, quad = lane >> 4;

    const u16* Qb = Q + ((size_t)b * HWD) * CD + nh * 64;
    const u16* Kb = K + ((size_t)b * HWD) * CD + nh * 64;
    const u16* Vb = Vt + ((size_t)bh * HDD) * HWD;

    // Q fragments (B operand of S^T): lane l15 = qrow
    short8 qf[2][2];
    #pragma unroll
    for (int qi = 0; qi < 2; ++qi) {
        const u16* qrow = Qb + (size_t)(qt * 128 + w * 32 + qi * 16 + l15) * CD + quad * 8;
        qf[qi][0] = *(const short8*)(qrow);
        qf[qi][1] = *(const short8*)(qrow + 32);
    }

    f32x4 acc_o[2][4];
    float psum[2] = {0.f, 0.f};
    #pragma unroll
    for (int qi = 0; qi < 2; ++qi)
        #pragma unroll
        for (int dj = 0; dj < 4; ++dj)
            acc_o[qi][dj] = (f32x4){0.f, 0.f, 0.f, 0.f};

    // base pointers for frag loads
    const u16* kbase = Kb + (size_t)(ks * 2048 + l15) * CD + quad * 8;
    const u16* vbase = Vb + (size_t)l15 * HWD + ks * 2048 + quad * 8;

    #pragma unroll 2
    for (int it = 0; it < 32; ++it) {
        // ---- K fragments (A operand): 8 x dwordx4 from global ----
        short8 kf[4][2];
        const u16* kp = kbase + (size_t)it * 64 * CD;
        #pragma unroll
        for (int nj = 0; nj < 4; ++nj)
            #pragma unroll
            for (int kk = 0; kk < 2; ++kk)
                kf[nj][kk] = *(const short8*)(kp + (size_t)nj * 16 * CD + kk * 32);
        // ---- V fragments (B operand): 8 x dwordx4 from global ----
        short8 vf[4][2];
        const u16* vp = vbase + it * 64;
        #pragma unroll
        for (int dj = 0; dj < 4; ++dj)
            #pragma unroll
            for (int kk = 0; kk < 2; ++kk)
                vf[dj][kk] = *(const short8*)(vp + (size_t)dj * 16 * HWD + kk * 32);

        // ---- S^T = K Q^T ----
        f32x4 st[4][2];
        #pragma unroll
        for (int nj = 0; nj < 4; ++nj)
            #pragma unroll
            for (int qi = 0; qi < 2; ++qi)
                st[nj][qi] = (f32x4){0.f, 0.f, 0.f, 0.f};
        #pragma unroll
        for (int kk = 0; kk < 2; ++kk)
            #pragma unroll
            for (int nj = 0; nj < 4; ++nj)
                #pragma unroll
                for (int qi = 0; qi < 2; ++qi)
                    st[nj][qi] = __builtin_amdgcn_mfma_f32_16x16x32_bf16(
                        kf[nj][kk], qf[qi][kk], st[nj][qi], 0, 0, 0);

        // ---- softmax numerators -> Ps (b64, wave-private rows) ----
        #pragma unroll
        for (int qi = 0; qi < 2; ++qi)
            #pragma unroll
            for (int nj = 0; nj < 4; ++nj) {
                float e0 = fexp2(st[nj][qi][0]);
                float e1 = fexp2(st[nj][qi][1]);
                float e2 = fexp2(st[nj][qi][2]);
                float e3 = fexp2(st[nj][qi][3]);
                psum[qi] += (e0 + e1) + (e2 + e3);
                uint2 pw;
                pw.x = pk2r(e0, e1);
                pw.y = pk2r(e2, e3);
                *(uint2*)&Ps[w * 32 + qi * 16 + l15][nj * 16 + quad * 4] = pw;
            }

        // ---- O += P V ----
        #pragma unroll
        for (int kk = 0; kk < 2; ++kk)
            #pragma unroll
            for (int qi = 0; qi < 2; ++qi) {
                short8 pf = *(const short8*)&Ps[w * 32 + qi * 16 + l15][kk * 32 + quad * 8];
                #pragma unroll
                for (int dj = 0; dj < 4; ++dj)
                    acc_o[qi][dj] = __builtin_amdgcn_mfma_f32_16x16x32_bf16(
                        pf, vf[dj][kk], acc_o[qi][dj], 0, 0, 0);
            }
    }

    // ---- write partials ----
    float* Ob = Opart + (((size_t)ks * 8 + bh) * HWD) * HDD;
    #pragma unroll
    for (int qi = 0; qi < 2; ++qi)
        #pragma unroll
        for (int dj = 0; dj < 4; ++dj)
            #pragma unroll
            for (int r = 0; r < 4; ++r) {
                int n = qt * 128 + w * 32 + qi * 16 + quad * 4 + r;
                Ob[(size_t)n * HDD + dj * 16 + l15] = acc_o[qi][dj][r];
            }

    float* Pb = Psum + ((size_t)ks * 8 + bh) * HWD + qt * 128 + w * 32;
    #pragma unroll
    for (int qi = 0; qi < 2; ++qi) {
        float s = psum[qi];
        s += __shfl_xor(s, 16);
        s += __shfl_xor(s, 32);
        if (quad == 0) Pb[qi * 16 + l15] = s;
    }
}

// ---------------------------------------------------------------------------
// out-proj GEMM + bias + residual, fp32 out; fuses the key-split combine:
// B-tile = (O0+O1) * 1/(p0+p1), packed to bf16 on the fly.
// grid (64 ptiles, 2 ctiles, 2 b), block 256. Register-prefetched K-loop.
// ---------------------------------------------------------------------------
__global__ __launch_bounds__(256) void out_gemm(
    const float* __restrict__ W, const float* __restrict__ Bi,
    const float* __restrict__ Opart, const float* __restrict__ Psum,
    const float* __restrict__ residual, float* __restrict__ out)
{
    int b = blockIdx.z;
    int m0 = blockIdx.y * 128;   // channels
    int n0 = blockIdx.x * 64;    // positions

    __shared__ u16 As[128][40];
    __shared__ u16 Bs[64][40];

    int tid = threadIdx.x;
    int lane = tid & 63, w = tid >> 6;
    int wm = w >> 1, wn = w & 1;
    int l15 = lane & 15, quad = lane >> 4;

    f32x4 acc[4][2];
    #pragma unroll
    for (int mi = 0; mi < 4; ++mi)
        #pragma unroll
        for (int nj = 0; nj < 2; ++nj)
            acc[mi][nj] = (f32x4){0.f, 0.f, 0.f, 0.f};

    int arow = tid >> 1, akh = (tid & 1) * 16;
    const float* wgp = W + (size_t)(m0 + arow) * CD + akh;
    int brow = tid >> 2, bseg = (tid & 3) * 8;
    int pn = n0 + brow;

    float4 rw0 = ((const float4*)wgp)[0], rw1 = ((const float4*)wgp)[1];
    float4 rw2 = ((const float4*)wgp)[2], rw3 = ((const float4*)wgp)[3];

    // B prefetch state for kt
    float4 a0, a1, b0, b1; float rinv;
    {
        int c = bseg;                 // kt = 0
        int bh = b * 4 + (c >> 6), d0 = c & 63;
        const float* O0 = Opart + (((size_t)bh) * HWD + pn) * HDD + d0;
        const float* O1 = Opart + (((size_t)8 + bh) * HWD + pn) * HDD + d0;
        a0 = ((const float4*)O0)[0]; a1 = ((const float4*)O0)[1];
        b0 = ((const float4*)O1)[0]; b1 = ((const float4*)O1)[1];
        float p = Psum[(size_t)bh * HWD + pn] + Psum[((size_t)8 + bh) * HWD + pn];
        rinv = 1.f / p;
    }

    for (int kt = 0; kt < 8; ++kt) {
        __syncthreads();
        {
            uint4 qa, qb;
            qa.x = pk2(rw0.x, rw0.y); qa.y = pk2(rw0.z, rw0.w);
            qa.z = pk2(rw1.x, rw1.y); qa.w = pk2(rw1.z, rw1.w);
            qb.x = pk2(rw2.x, rw2.y); qb.y = pk2(rw2.z, rw2.w);
            qb.z = pk2(rw3.x, rw3.y); qb.w = pk2(rw3.z, rw3.w);
            *(uint4*)&As[arow][akh] = qa;
            *(uint4*)&As[arow][akh + 8] = qb;
        }
        {
            uint4 bb;
            bb.x = pk2((a0.x + b0.x) * rinv, (a0.y + b0.y) * rinv);
            bb.y = pk2((a0.z + b0.z) * rinv, (a0.w + b0.w) * rinv);
            bb.z = pk2((a1.x + b1.x) * rinv, (a1.y + b1.y) * rinv);
            bb.w = pk2((a1.z + b1.z) * rinv, (a1.w + b1.w) * rinv);
            *(uint4*)&Bs[brow][bseg] = bb;
        }
        if (kt < 7) {
            const float* wg2 = wgp + (kt + 1) * 32;
            rw0 = ((const float4*)wg2)[0]; rw1 = ((const float4*)wg2)[1];
            rw2 = ((const float4*)wg2)[2]; rw3 = ((const float4*)wg2)[3];
            int c = (kt + 1) * 32 + bseg;
            int bh = b * 4 + (c >> 6), d0 = c & 63;
            const float* O0 = Opart + (((size_t)bh) * HWD + pn) * HDD + d0;
            const float* O1 = Opart + (((size_t)8 + bh) * HWD + pn) * HDD + d0;
            a0 = ((const float4*)O0)[0]; a1 = ((const float4*)O0)[1];
            b0 = ((const float4*)O1)[0]; b1 = ((const float4*)O1)[1];
            float p = Psum[(size_t)bh * HWD + pn] + Psum[((size_t)8 + bh) * HWD + pn];
            rinv = 1.f / p;
        }
        __syncthreads();

        short8 af[4], bf[2];
        #pragma unroll
        for (int mi = 0; mi < 4; ++mi)
            af[mi] = *(const short8*)&As[wm * 64 + mi * 16 + l15][quad * 8];
        #pragma unroll
        for (int nj = 0; nj < 2; ++nj)
            bf[nj] = *(const short8*)&Bs[wn * 32 + nj * 16 + l15][quad * 8];
        #pragma unroll
        for (int mi = 0; mi < 4; ++mi)
            #pragma unroll
            for (int nj = 0; nj < 2; ++nj)
                acc[mi][nj] = __builtin_amdgcn_mfma_f32_16x16x32_bf16(
                    af[mi], bf[nj], acc[mi][nj], 0, 0, 0);
    }

    #pragma unroll
    for (int mi = 0; mi < 4; ++mi) {
        int mb = m0 + wm * 64 + mi * 16 + quad * 4;
        #pragma unroll
        for (int r = 0; r < 4; ++r) {
            float bias = Bi[mb + r];
            const float* res = residual + (size_t)(b * CD + mb + r) * HWD;
            float* o = out + (size_t)(b * CD + mb + r) * HWD;
            #pragma unroll
            for (int nj = 0; nj < 2; ++nj) {
                int n = n0 + wn * 32 + nj * 16 + l15;
                o[n] = acc[mi][nj][r] + bias + res[n];
            }
        }
    }
}

extern "C" void kernel_launch(void* const* d_in, const int* in_sizes, int n_in,
                              void* d_out, int out_size, void* d_ws, size_t ws_size,
                              hipStream_t stream) {
    (void)in_sizes; (void)n_in; (void)out_size; (void)ws_size;

    const float* image = (const float*)d_in[0];
    const float* guide = (const float*)d_in[1];
    const float* ln1_g = (const float*)d_in[2];
    const float* ln1_b = (const float*)d_in[3];
    const float* ln2_g = (const float*)d_in[4];
    const float* ln2_b = (const float*)d_in[5];
    const float* qw1 = (const float*)d_in[6];
    const float* qb1 = (const float*)d_in[7];
    const float* qw2 = (const float*)d_in[8];
    const float* qb2 = (const float*)d_in[9];
    const float* kw1 = (const float*)d_in[10];
    const float* kb1 = (const float*)d_in[11];
    const float* kw2 = (const float*)d_in[12];
    const float* kb2 = (const float*)d_in[13];
    const float* vw1 = (const float*)d_in[14];
    const float* vb1 = (const float*)d_in[15];
    const float* vw2 = (const float*)d_in[16];
    const float* vb2 = (const float*)d_in[17];
    const float* ow  = (const float*)d_in[18];
    const float* ob  = (const float*)d_in[19];
    float* out = (float*)d_out;

    char* ws = (char*)d_ws;
    // phase 1/2 buffers (dead before attn writes partials over them)
    u16* xT    = (u16*)(ws + (size_t)0  * (1 << 20));
    u16* gT    = (u16*)(ws + (size_t)4  * (1 << 20));
    u16* q1    = (u16*)(ws + (size_t)8  * (1 << 20));
    u16* k1    = (u16*)(ws + (size_t)12 * (1 << 20));
    u16* v1    = (u16*)(ws + (size_t)16 * (1 << 20));
    u16* Qh    = (u16*)(ws + (size_t)20 * (1 << 20));
    u16* Kh    = (u16*)(ws + (size_t)24 * (1 << 20));
    u16* Vt    = (u16*)(ws + (size_t)28 * (1 << 20));
    // attn partials: Opart 16 MB over xT/gT/q1/k1, Psum 256 KB over v1
    float* Opart = (float*)(ws + (size_t)0  * (1 << 20));
    float* Psum  = (float*)(ws + (size_t)16 * (1 << 20));

    ln_transpose<<<dim3(256), dim3(256), 0, stream>>>(
        image, guide, ln1_g, ln1_b, ln2_g, ln2_b, xT, gT);

    qkv_gemm<<<dim3(2, 32, 6), dim3(256), 0, stream>>>(
        xT, gT, qw1, qb1, kw1, kb1, vw1, vb1, q1, k1, v1);

    dwconv_nc<<<dim3(1536), dim3(256), 0, stream>>>(
        q1, k1, v1, qw2, qb2, kw2, kb2, vw2, vb2, Qh, Kh, Vt);

    attn_kernel<<<dim3(32, 8, 2), dim3(256), 0, stream>>>(Qh, Kh, Vt, Opart, Psum);

    out_gemm<<<dim3(64, 2, 2), dim3(256), 0, stream>>>(
        ow, ob, Opart, Psum, image, out);
}

// Round 7
// 195.542 us; speedup vs baseline: 1.3261x; 1.3261x over previous
//
#include <hip/hip_runtime.h>
#include <cstdint>
#include <cstddef>

typedef unsigned short u16;
typedef unsigned int u32;
typedef __attribute__((ext_vector_type(8))) short short8;
typedef __attribute__((ext_vector_type(4))) float f32x4;

#define CD 256
#define HWD 4096
#define NHD 4
#define HDD 64

static __device__ __forceinline__ u16 f2b(float f) {
    u32 u = __builtin_bit_cast(u32, f);
    return (u16)((u + 0x7fffu + ((u >> 16) & 1u)) >> 16);
}
static __device__ __forceinline__ float b2f(u16 h) {
    return __builtin_bit_cast(float, (u32)h << 16);
}
static __device__ __forceinline__ u32 pk2(float a, float b) {
    return (u32)f2b(a) | ((u32)f2b(b) << 16);
}
// cheap round-half-up bf16 pack (positive values; bias cancels in softmax ratio)
static __device__ __forceinline__ u32 pk2r(float a, float b) {
    u32 ua = __builtin_bit_cast(u32, a) + 0x8000u;
    u32 ub = __builtin_bit_cast(u32, b) + 0x8000u;
    return (ua >> 16) | (ub & 0xffff0000u);
}
static __device__ __forceinline__ float fexp2(float x) {
#if __has_builtin(__builtin_amdgcn_exp2f)
    return __builtin_amdgcn_exp2f(x);
#else
    return __expf(x * 0.69314718056f);
#endif
}
// async global->LDS DMA, 16 B per lane; LDS dest = wave-uniform base + lane*16
static __device__ __forceinline__ void async16(const void* g, void* l) {
    __builtin_amdgcn_global_load_lds(
        (const __attribute__((address_space(1))) unsigned int*)g,
        (__attribute__((address_space(3))) unsigned int*)l,
        16, 0, 0);
}

// ---------------------------------------------------------------------------
// LayerNorm over C + transpose to bf16 [b][p][c].
// grid 256: bid>>7 = tensor, (bid>>6)&1 = b, (bid&63)*64 = p0. block 256.
// ---------------------------------------------------------------------------
__global__ __launch_bounds__(256) void ln_transpose(
    const float* __restrict__ x0, const float* __restrict__ x1,
    const float* __restrict__ g0, const float* __restrict__ b0,
    const float* __restrict__ g1, const float* __restrict__ b1,
    u16* __restrict__ out0, u16* __restrict__ out1)
{
    int bid = blockIdx.x;
    int t = bid >> 7, b = (bid >> 6) & 1, p0 = (bid & 63) << 6;
    const float* x = t ? x1 : x0;
    const float* g = t ? g1 : g0;
    const float* bb = t ? b1 : b0;
    u16* out = t ? out1 : out0;

    int tid = threadIdx.x;
    int tx = tid & 63, ty = tid >> 6;
    const float* xb = x + (size_t)b * CD * HWD + p0 + tx;

    __shared__ float red[2][4][64];
    __shared__ u16 T[256][65];

    float s = 0.f, sq = 0.f;
    #pragma unroll 8
    for (int i = 0; i < 64; ++i) {
        float v = xb[(size_t)(ty * 64 + i) * HWD];
        s += v; sq += v * v;
    }
    red[0][ty][tx] = s; red[1][ty][tx] = sq;
    __syncthreads();
    float st  = red[0][0][tx] + red[0][1][tx] + red[0][2][tx] + red[0][3][tx];
    float sqt = red[1][0][tx] + red[1][1][tx] + red[1][2][tx] + red[1][3][tx];
    float mean = st * (1.f / 256.f);
    float var = sqt * (1.f / 256.f) - mean * mean;
    float rstd = rsqrtf(var + 1e-5f);

    #pragma unroll 8
    for (int i = 0; i < 64; ++i) {
        int c = ty * 64 + i;
        float v = (xb[(size_t)c * HWD] - mean) * rstd * g[c] + bb[c];
        T[c][tx] = f2b(v);
    }
    __syncthreads();

    int pr = tid >> 5, c0 = (tid & 31) * 8;
    #pragma unroll
    for (int pass = 0; pass < 8; ++pass) {
        int p = pass * 8 + pr;
        u16 tmp[8];
        #pragma unroll
        for (int j = 0; j < 8; ++j) tmp[j] = T[c0 + j][p];
        *(uint4*)&out[((size_t)b * HWD + p0 + p) * CD + c0] = *(const uint4*)tmp;
    }
}

// ---------------------------------------------------------------------------
// conv1x1 GEMM, bf16 [p][c] input, register-prefetched K-loop.
// grid (2 ctiles, 32 ptiles, 6 = mm*2+b), block 256.
// ---------------------------------------------------------------------------
__global__ __launch_bounds__(256) void qkv_gemm(
    const u16* __restrict__ xT, const u16* __restrict__ gT,
    const float* __restrict__ qw1, const float* __restrict__ qb1,
    const float* __restrict__ kw1, const float* __restrict__ kb1,
    const float* __restrict__ vw1, const float* __restrict__ vb1,
    u16* __restrict__ q1, u16* __restrict__ k1, u16* __restrict__ v1)
{
    int z = blockIdx.z;
    int mm = z >> 1, b = z & 1;
    const u16* X    = (mm == 0) ? xT : gT;
    const float* W  = (mm == 0) ? qw1 : (mm == 1) ? kw1 : vw1;
    const float* Bi = (mm == 0) ? qb1 : (mm == 1) ? kb1 : vb1;
    u16* Y          = (mm == 0) ? q1 : (mm == 1) ? k1 : v1;

    int n0 = blockIdx.x * 128;
    int p0 = blockIdx.y * 128;

    __shared__ u16 As[128][40];
    __shared__ u16 Bs[128][40];

    int tid = threadIdx.x;
    int lane = tid & 63, w = tid >> 6;
    int wm = w >> 1, wn = w & 1;
    int l15 = lane & 15, quad = lane >> 4;

    f32x4 acc[4][4];
    #pragma unroll
    for (int mi = 0; mi < 4; ++mi)
        #pragma unroll
        for (int nj = 0; nj < 4; ++nj)
            acc[mi][nj] = (f32x4){0.f, 0.f, 0.f, 0.f};

    const u16* Xb = X + (size_t)b * HWD * CD;

    int arow = tid >> 1, akh = (tid & 1) * 16;
    const u16* agp = Xb + (size_t)(p0 + arow) * CD + akh;
    const float* wgp = W + (size_t)(n0 + arow) * CD + akh;

    uint4 ra0 = *(const uint4*)(agp);
    uint4 ra1 = *(const uint4*)(agp + 8);
    float4 rw0 = ((const float4*)wgp)[0], rw1 = ((const float4*)wgp)[1];
    float4 rw2 = ((const float4*)wgp)[2], rw3 = ((const float4*)wgp)[3];

    for (int kt = 0; kt < 8; ++kt) {
        __syncthreads();
        *(uint4*)&As[arow][akh] = ra0;
        *(uint4*)&As[arow][akh + 8] = ra1;
        {
            uint4 qa, qb;
            qa.x = pk2(rw0.x, rw0.y); qa.y = pk2(rw0.z, rw0.w);
            qa.z = pk2(rw1.x, rw1.y); qa.w = pk2(rw1.z, rw1.w);
            qb.x = pk2(rw2.x, rw2.y); qb.y = pk2(rw2.z, rw2.w);
            qb.z = pk2(rw3.x, rw3.y); qb.w = pk2(rw3.z, rw3.w);
            *(uint4*)&Bs[arow][akh] = qa;
            *(uint4*)&Bs[arow][akh + 8] = qb;
        }
        if (kt < 7) {
            const u16* ag2 = agp + (kt + 1) * 32;
            const float* wg2 = wgp + (kt + 1) * 32;
            ra0 = *(const uint4*)(ag2);
            ra1 = *(const uint4*)(ag2 + 8);
            rw0 = ((const float4*)wg2)[0]; rw1 = ((const float4*)wg2)[1];
            rw2 = ((const float4*)wg2)[2]; rw3 = ((const float4*)wg2)[3];
        }
        __syncthreads();

        short8 af[4], bf[4];
        #pragma unroll
        for (int mi = 0; mi < 4; ++mi)
            af[mi] = *(const short8*)&As[wm * 64 + mi * 16 + l15][quad * 8];
        #pragma unroll
        for (int nj = 0; nj < 4; ++nj)
            bf[nj] = *(const short8*)&Bs[wn * 64 + nj * 16 + l15][quad * 8];
        #pragma unroll
        for (int mi = 0; mi < 4; ++mi)
            #pragma unroll
            for (int nj = 0; nj < 4; ++nj)
                acc[mi][nj] = __builtin_amdgcn_mfma_f32_16x16x32_bf16(
                    af[mi], bf[nj], acc[mi][nj], 0, 0, 0);
    }

    u16* Yb = Y + (size_t)b * HWD * CD;
    float bias[4];
    #pragma unroll
    for (int nj = 0; nj < 4; ++nj)
        bias[nj] = Bi[n0 + wn * 64 + nj * 16 + l15];
    #pragma unroll
    for (int mi = 0; mi < 4; ++mi) {
        #pragma unroll
        for (int r = 0; r < 4; ++r) {
            int p = p0 + wm * 64 + mi * 16 + quad * 4 + r;
            #pragma unroll
            for (int nj = 0; nj < 4; ++nj) {
                int ch = n0 + wn * 64 + nj * 16 + l15;
                Yb[(size_t)p * CD + ch] = f2b(acc[mi][nj][r] + bias[nj]);
            }
        }
    }
}

// ---------------------------------------------------------------------------
// depthwise 3x3 SAME + bias; q scaled by 0.125*log2(e) (softmax in exp2 domain).
// Q,K out [b][n][c]; V out transposed [b*256+c][n].
// grid 1536, block 256 (lane = channel).
// ---------------------------------------------------------------------------
__global__ __launch_bounds__(256) void dwconv_nc(
    const u16* __restrict__ q1, const u16* __restrict__ k1, const u16* __restrict__ v1,
    const float* __restrict__ qw2, const float* __restrict__ qb2,
    const float* __restrict__ kw2, const float* __restrict__ kb2,
    const float* __restrict__ vw2, const float* __restrict__ vb2,
    u16* __restrict__ Q, u16* __restrict__ K, u16* __restrict__ Vt)
{
    int bid = blockIdx.x;
    int which = bid >> 9;
    int b = (bid >> 8) & 1;
    int p0 = (bid & 255) * 16;

    const u16* in = ((which == 0) ? q1 : (which == 1) ? k1 : v1) + (size_t)b * HWD * CD;
    const float* wsrc = (which == 0) ? qw2 : (which == 1) ? kw2 : vw2;
    const float* bsrc = (which == 0) ? qb2 : (which == 1) ? kb2 : vb2;
    float oscale = (which == 0) ? 0.18033688011112042f : 1.0f;

    int c = threadIdx.x;
    float w9[9];
    #pragma unroll
    for (int j = 0; j < 9; ++j) w9[j] = wsrc[c * 9 + j];
    float bias = bsrc[c];

    int h = p0 >> 6, w0 = p0 & 63;

    float accv[16];
    #pragma unroll
    for (int pi = 0; pi < 16; ++pi) accv[pi] = bias;

    #pragma unroll
    for (int dh = -1; dh <= 1; ++dh) {
        int hh = h + dh;
        if (hh < 0 || hh >= 64) continue;
        #pragma unroll
        for (int dw = -1; dw <= 1; ++dw) {
            float wt = w9[(dh + 1) * 3 + (dw + 1)];
            #pragma unroll
            for (int pi = 0; pi < 16; ++pi) {
                int wc = w0 + pi + dw;
                if (wc < 0 || wc >= 64) continue;
                int np = hh * 64 + wc;
                accv[pi] += wt * b2f(in[(size_t)np * CD + c]);
            }
        }
    }

    if (which == 2) {
        u32 w8[8];
        #pragma unroll
        for (int j = 0; j < 8; ++j) w8[j] = pk2(accv[2 * j], accv[2 * j + 1]);
        uint4* dst = (uint4*)(Vt + ((size_t)(b * CD + c)) * HWD + p0);
        dst[0] = make_uint4(w8[0], w8[1], w8[2], w8[3]);
        dst[1] = make_uint4(w8[4], w8[5], w8[6], w8[7]);
    } else {
        u16* out = ((which == 0) ? Q : K) + (size_t)b * HWD * CD;
        #pragma unroll
        for (int pi = 0; pi < 16; ++pi)
            out[(size_t)(p0 + pi) * CD + c] = f2b(accv[pi] * oscale);
    }
}

// ---------------------------------------------------------------------------
// Flash attention (S^T), key-split x2, async double-buffered LDS staging.
// BM=128 qrows (32/wave), BN=64 keys/iter, 32 iters. K/V staged by
// global_load_lds width=16 into XOR-swizzled unpadded LDS (swizzle applied
// on the global address side; 2-way max bank aliasing everywhere).
// One barrier per iter; 2 blocks/CU hide each other's drains.
// Partials (unnormalized fp32 O, psum) combined in out_gemm.
// grid (32 qtiles, 8 bh, 2 ks), block 256. LDS 48 KB.
// ---------------------------------------------------------------------------
__global__ __launch_bounds__(256, 2) void attn_kernel(
    const u16* __restrict__ Q, const u16* __restrict__ K,
    const u16* __restrict__ Vt, float* __restrict__ Opart,
    float* __restrict__ Psum)
{
    int qt = blockIdx.x;
    int bh = blockIdx.y;
    int ks = blockIdx.z;
    int b = bh >> 2, nh = bh & 3;

    __shared__ u16 Ks[2][64 * 64];   // [key][d], granule-swizzled
    __shared__ u16 Vs[2][64 * 64];   // [d][key], granule-swizzled
    __shared__ u16 Ps[128 * 64];     // [qrow][key], granule-swizzled, wave-private rows

    int tid = threadIdx.x;
    int lane = tid & 63, w = tid >> 6;
    int l15 = lane & 15, quad = lane >> 4;
    int sw = l15 & 7;                // reader-side swizzle mask

    const u16* Qb = Q + ((size_t)b * HWD) * CD + nh * 64;
    const u16* Kb = K + ((size_t)b * HWD) * CD + nh * 64;
    const u16* Vb = Vt + ((size_t)bh * HDD) * HWD;

    // Q fragments (B operand of S^T): lane l15 = qrow
    short8 qf[2][2];
    #pragma unroll
    for (int qi = 0; qi < 2; ++qi) {
        const u16* qrow = Qb + (size_t)(qt * 128 + w * 32 + qi * 16 + l15) * CD + quad * 8;
        qf[qi][0] = *(const short8*)(qrow);
        qf[qi][1] = *(const short8*)(qrow + 32);
    }

    // staging: wave w covers 16 rows; lane -> (row rr, LDS seg lane&7) holding
    // global granule (lane&7)^rr  (so LDS[row][s] = global granule s^(row&7))
    int rr = lane >> 3;
    int gseg = (lane & 7) ^ rr;
    const u16* kgb = Kb + (size_t)(ks * 2048 + w * 16 + rr) * CD + gseg * 8;
    const u16* vgb = Vb + (size_t)(w * 16 + rr) * HWD + ks * 2048 + gseg * 8;

    f32x4 acc_o[2][4];
    float psum[2] = {0.f, 0.f};
    #pragma unroll
    for (int qi = 0; qi < 2; ++qi)
        #pragma unroll
        for (int dj = 0; dj < 4; ++dj)
            acc_o[qi][dj] = (f32x4){0.f, 0.f, 0.f, 0.f};

    // prefetch tile 0 into buf 0
    #pragma unroll
    for (int j = 0; j < 2; ++j) {
        async16(kgb + (size_t)(j * 8) * CD, &Ks[0][(w * 16 + j * 8) * 64]);
        async16(vgb + (size_t)(j * 8) * HWD, &Vs[0][(w * 16 + j * 8) * 64]);
    }

    for (int it = 0; it < 32; ++it) {
        int cur = it & 1;
        __syncthreads();   // drains DMA for tile it; all waves done reading buf cur
        if (it + 1 < 32) {
            int nxt = cur ^ 1;
            #pragma unroll
            for (int j = 0; j < 2; ++j) {
                async16(kgb + (size_t)((it + 1) * 64 + j * 8) * CD,
                        &Ks[nxt][(w * 16 + j * 8) * 64]);
                async16(vgb + (size_t)(j * 8) * HWD + (it + 1) * 64,
                        &Vs[nxt][(w * 16 + j * 8) * 64]);
            }
        }

        // ---- fragments from swizzled LDS ----
        short8 kf[4][2], vf[4][2];
        #pragma unroll
        for (int nj = 0; nj < 4; ++nj)
            #pragma unroll
            for (int kk = 0; kk < 2; ++kk)
                kf[nj][kk] = *(const short8*)&Ks[cur][(nj * 16 + l15) * 64 +
                                                     (((kk * 4 + quad) ^ sw) << 3)];
        #pragma unroll
        for (int dj = 0; dj < 4; ++dj)
            #pragma unroll
            for (int kk = 0; kk < 2; ++kk)
                vf[dj][kk] = *(const short8*)&Vs[cur][(dj * 16 + l15) * 64 +
                                                     (((kk * 4 + quad) ^ sw) << 3)];

        // ---- S^T = K Q^T ----
        f32x4 st[4][2];
        #pragma unroll
        for (int nj = 0; nj < 4; ++nj)
            #pragma unroll
            for (int qi = 0; qi < 2; ++qi)
                st[nj][qi] = (f32x4){0.f, 0.f, 0.f, 0.f};
        #pragma unroll
        for (int kk = 0; kk < 2; ++kk)
            #pragma unroll
            for (int nj = 0; nj < 4; ++nj)
                #pragma unroll
                for (int qi = 0; qi < 2; ++qi)
                    st[nj][qi] = __builtin_amdgcn_mfma_f32_16x16x32_bf16(
                        kf[nj][kk], qf[qi][kk], st[nj][qi], 0, 0, 0);

        // ---- softmax numerators -> Ps (b64 swizzled, wave-private rows) ----
        #pragma unroll
        for (int qi = 0; qi < 2; ++qi) {
            int prow = (w * 32 + qi * 16 + l15) * 64;
            #pragma unroll
            for (int nj = 0; nj < 4; ++nj) {
                float e0 = fexp2(st[nj][qi][0]);
                float e1 = fexp2(st[nj][qi][1]);
                float e2 = fexp2(st[nj][qi][2]);
                float e3 = fexp2(st[nj][qi][3]);
                psum[qi] += (e0 + e1) + (e2 + e3);
                uint2 pw;
                pw.x = pk2r(e0, e1);
                pw.y = pk2r(e2, e3);
                int pcol = (((nj * 2 + (quad >> 1)) ^ sw) << 3) + (quad & 1) * 4;
                *(uint2*)&Ps[prow + pcol] = pw;
            }
        }

        // ---- O += P V  (same-wave DS ordering; no barrier) ----
        #pragma unroll
        for (int kk = 0; kk < 2; ++kk)
            #pragma unroll
            for (int qi = 0; qi < 2; ++qi) {
                short8 pf = *(const short8*)&Ps[(w * 32 + qi * 16 + l15) * 64 +
                                                (((kk * 4 + quad) ^ sw) << 3)];
                #pragma unroll
                for (int dj = 0; dj < 4; ++dj)
                    acc_o[qi][dj] = __builtin_amdgcn_mfma_f32_16x16x32_bf16(
                        pf, vf[dj][kk], acc_o[qi][dj], 0, 0, 0);
            }
    }

    // ---- write partials ----
    float* Ob = Opart + (((size_t)ks * 8 + bh) * HWD) * HDD;
    #pragma unroll
    for (int qi = 0; qi < 2; ++qi)
        #pragma unroll
        for (int dj = 0; dj < 4; ++dj)
            #pragma unroll
            for (int r = 0; r < 4; ++r) {
                int n = qt * 128 + w * 32 + qi * 16 + quad * 4 + r;
                Ob[(size_t)n * HDD + dj * 16 + l15] = acc_o[qi][dj][r];
            }

    float* Pb = Psum + ((size_t)ks * 8 + bh) * HWD + qt * 128 + w * 32;
    #pragma unroll
    for (int qi = 0; qi < 2; ++qi) {
        float s = psum[qi];
        s += __shfl_xor(s, 16);
        s += __shfl_xor(s, 32);
        if (quad == 0) Pb[qi * 16 + l15] = s;
    }
}

// ---------------------------------------------------------------------------
// out-proj GEMM + bias + residual, fp32 out; fuses the key-split combine:
// B-tile = (O0+O1) * 1/(p0+p1), packed to bf16 on the fly.
// grid (64 ptiles, 2 ctiles, 2 b), block 256. Register-prefetched K-loop.
// ---------------------------------------------------------------------------
__global__ __launch_bounds__(256) void out_gemm(
    const float* __restrict__ W, const float* __restrict__ Bi,
    const float* __restrict__ Opart, const float* __restrict__ Psum,
    const float* __restrict__ residual, float* __restrict__ out)
{
    int b = blockIdx.z;
    int m0 = blockIdx.y * 128;   // channels
    int n0 = blockIdx.x * 64;    // positions

    __shared__ u16 As[128][40];
    __shared__ u16 Bs[64][40];

    int tid = threadIdx.x;
    int lane = tid & 63, w = tid >> 6;
    int wm = w >> 1, wn = w & 1;
    int l15 = lane & 15, quad = lane >> 4;

    f32x4 acc[4][2];
    #pragma unroll
    for (int mi = 0; mi < 4; ++mi)
        #pragma unroll
        for (int nj = 0; nj < 2; ++nj)
            acc[mi][nj] = (f32x4){0.f, 0.f, 0.f, 0.f};

    int arow = tid >> 1, akh = (tid & 1) * 16;
    const float* wgp = W + (size_t)(m0 + arow) * CD + akh;
    int brow = tid >> 2, bseg = (tid & 3) * 8;
    int pn = n0 + brow;

    float4 rw0 = ((const float4*)wgp)[0], rw1 = ((const float4*)wgp)[1];
    float4 rw2 = ((const float4*)wgp)[2], rw3 = ((const float4*)wgp)[3];

    float4 a0, a1, b0, b1; float rinv;
    {
        int c = bseg;
        int bh = b * 4 + (c >> 6), d0 = c & 63;
        const float* O0 = Opart + (((size_t)bh) * HWD + pn) * HDD + d0;
        const float* O1 = Opart + (((size_t)8 + bh) * HWD + pn) * HDD + d0;
        a0 = ((const float4*)O0)[0]; a1 = ((const float4*)O0)[1];
        b0 = ((const float4*)O1)[0]; b1 = ((const float4*)O1)[1];
        float p = Psum[(size_t)bh * HWD + pn] + Psum[((size_t)8 + bh) * HWD + pn];
        rinv = 1.f / p;
    }

    for (int kt = 0; kt < 8; ++kt) {
        __syncthreads();
        {
            uint4 qa, qb;
            qa.x = pk2(rw0.x, rw0.y); qa.y = pk2(rw0.z, rw0.w);
            qa.z = pk2(rw1.x, rw1.y); qa.w = pk2(rw1.z, rw1.w);
            qb.x = pk2(rw2.x, rw2.y); qb.y = pk2(rw2.z, rw2.w);
            qb.z = pk2(rw3.x, rw3.y); qb.w = pk2(rw3.z, rw3.w);
            *(uint4*)&As[arow][akh] = qa;
            *(uint4*)&As[arow][akh + 8] = qb;
        }
        {
            uint4 bb;
            bb.x = pk2((a0.x + b0.x) * rinv, (a0.y + b0.y) * rinv);
            bb.y = pk2((a0.z + b0.z) * rinv, (a0.w + b0.w) * rinv);
            bb.z = pk2((a1.x + b1.x) * rinv, (a1.y + b1.y) * rinv);
            bb.w = pk2((a1.z + b1.z) * rinv, (a1.w + b1.w) * rinv);
            *(uint4*)&Bs[brow][bseg] = bb;
        }
        if (kt < 7) {
            const float* wg2 = wgp + (kt + 1) * 32;
            rw0 = ((const float4*)wg2)[0]; rw1 = ((const float4*)wg2)[1];
            rw2 = ((const float4*)wg2)[2]; rw3 = ((const float4*)wg2)[3];
            int c = (kt + 1) * 32 + bseg;
            int bh = b * 4 + (c >> 6), d0 = c & 63;
            const float* O0 = Opart + (((size_t)bh) * HWD + pn) * HDD + d0;
            const float* O1 = Opart + (((size_t)8 + bh) * HWD + pn) * HDD + d0;
            a0 = ((const float4*)O0)[0]; a1 = ((const float4*)O0)[1];
            b0 = ((const float4*)O1)[0]; b1 = ((const float4*)O1)[1];
            float p = Psum[(size_t)bh * HWD + pn] + Psum[((size_t)8 + bh) * HWD + pn];
            rinv = 1.f / p;
        }
        __syncthreads();

        short8 af[4], bf[2];
        #pragma unroll
        for (int mi = 0; mi < 4; ++mi)
            af[mi] = *(const short8*)&As[wm * 64 + mi * 16 + l15][quad * 8];
        #pragma unroll
        for (int nj = 0; nj < 2; ++nj)
            bf[nj] = *(const short8*)&Bs[wn * 32 + nj * 16 + l15][quad * 8];
        #pragma unroll
        for (int mi = 0; mi < 4; ++mi)
            #pragma unroll
            for (int nj = 0; nj < 2; ++nj)
                acc[mi][nj] = __builtin_amdgcn_mfma_f32_16x16x32_bf16(
                    af[mi], bf[nj], acc[mi][nj], 0, 0, 0);
    }

    #pragma unroll
    for (int mi = 0; mi < 4; ++mi) {
        int mb = m0 + wm * 64 + mi * 16 + quad * 4;
        #pragma unroll
        for (int r = 0; r < 4; ++r) {
            float bias = Bi[mb + r];
            const float* res = residual + (size_t)(b * CD + mb + r) * HWD;
            float* o = out + (size_t)(b * CD + mb + r) * HWD;
            #pragma unroll
            for (int nj = 0; nj < 2; ++nj) {
                int n = n0 + wn * 32 + nj * 16 + l15;
                o[n] = acc[mi][nj][r] + bias + res[n];
            }
        }
    }
}

extern "C" void kernel_launch(void* const* d_in, const int* in_sizes, int n_in,
                              void* d_out, int out_size, void* d_ws, size_t ws_size,
                              hipStream_t stream) {
    (void)in_sizes; (void)n_in; (void)out_size; (void)ws_size;

    const float* image = (const float*)d_in[0];
    const float* guide = (const float*)d_in[1];
    const float* ln1_g = (const float*)d_in[2];
    const float* ln1_b = (const float*)d_in[3];
    const float* ln2_g = (const float*)d_in[4];
    const float* ln2_b = (const float*)d_in[5];
    const float* qw1 = (const float*)d_in[6];
    const float* qb1 = (const float*)d_in[7];
    const float* qw2 = (const float*)d_in[8];
    const float* qb2 = (const float*)d_in[9];
    const float* kw1 = (const float*)d_in[10];
    const float* kb1 = (const float*)d_in[11];
    const float* kw2 = (const float*)d_in[12];
    const float* kb2 = (const float*)d_in[13];
    const float* vw1 = (const float*)d_in[14];
    const float* vb1 = (const float*)d_in[15];
    const float* vw2 = (const float*)d_in[16];
    const float* vb2 = (const float*)d_in[17];
    const float* ow  = (const float*)d_in[18];
    const float* ob  = (const float*)d_in[19];
    float* out = (float*)d_out;

    char* ws = (char*)d_ws;
    u16* xT    = (u16*)(ws + (size_t)0  * (1 << 20));
    u16* gT    = (u16*)(ws + (size_t)4  * (1 << 20));
    u16* q1    = (u16*)(ws + (size_t)8  * (1 << 20));
    u16* k1    = (u16*)(ws + (size_t)12 * (1 << 20));
    u16* v1    = (u16*)(ws + (size_t)16 * (1 << 20));
    u16* Qh    = (u16*)(ws + (size_t)20 * (1 << 20));
    u16* Kh    = (u16*)(ws + (size_t)24 * (1 << 20));
    u16* Vt    = (u16*)(ws + (size_t)28 * (1 << 20));
    // attn partials overlay dead phase-1 buffers
    float* Opart = (float*)(ws + (size_t)0  * (1 << 20));
    float* Psum  = (float*)(ws + (size_t)16 * (1 << 20));

    ln_transpose<<<dim3(256), dim3(256), 0, stream>>>(
        image, guide, ln1_g, ln1_b, ln2_g, ln2_b, xT, gT);

    qkv_gemm<<<dim3(2, 32, 6), dim3(256), 0, stream>>>(
        xT, gT, qw1, qb1, kw1, kb1, vw1, vb1, q1, k1, v1);

    dwconv_nc<<<dim3(1536), dim3(256), 0, stream>>>(
        q1, k1, v1, qw2, qb2, kw2, kb2, vw2, vb2, Qh, Kh, Vt);

    attn_kernel<<<dim3(32, 8, 2), dim3(256), 0, stream>>>(Qh, Kh, Vt, Opart, Psum);

    out_gemm<<<dim3(64, 2, 2), dim3(256), 0, stream>>>(
        ow, ob, Opart, Psum, image, out);
}

// Round 8
// 188.942 us; speedup vs baseline: 1.3724x; 1.0349x over previous
//
#include <hip/hip_runtime.h>
#include <cstdint>
#include <cstddef>

typedef unsigned short u16;
typedef unsigned int u32;
typedef __attribute__((ext_vector_type(8))) short short8;
typedef __attribute__((ext_vector_type(4))) float f32x4;

#define CD 256
#define HWD 4096
#define NHD 4
#define HDD 64

static __device__ __forceinline__ u16 f2b(float f) {
    u32 u = __builtin_bit_cast(u32, f);
    return (u16)((u + 0x7fffu + ((u >> 16) & 1u)) >> 16);
}
static __device__ __forceinline__ float b2f(u16 h) {
    return __builtin_bit_cast(float, (u32)h << 16);
}
static __device__ __forceinline__ u32 pk2(float a, float b) {
    return (u32)f2b(a) | ((u32)f2b(b) << 16);
}
// cheap round-half-up bf16 pack (positive values; bias cancels in softmax ratio)
static __device__ __forceinline__ u32 pk2r(float a, float b) {
    u32 ua = __builtin_bit_cast(u32, a) + 0x8000u;
    u32 ub = __builtin_bit_cast(u32, b) + 0x8000u;
    return (ua >> 16) | (ub & 0xffff0000u);
}
static __device__ __forceinline__ float fexp2(float x) {
#if __has_builtin(__builtin_amdgcn_exp2f)
    return __builtin_amdgcn_exp2f(x);
#else
    return __expf(x * 0.69314718056f);
#endif
}
// async global->LDS DMA, 16 B per lane; LDS dest = wave-uniform base + lane*16
static __device__ __forceinline__ void async16(const void* g, void* l) {
    __builtin_amdgcn_global_load_lds(
        (const __attribute__((address_space(1))) unsigned int*)g,
        (__attribute__((address_space(3))) unsigned int*)l,
        16, 0, 0);
}

// ---------------------------------------------------------------------------
// LayerNorm over C + transpose to bf16 [b][p][c].
// grid 256: bid>>7 = tensor, (bid>>6)&1 = b, (bid&63)*64 = p0. block 256.
// ---------------------------------------------------------------------------
__global__ __launch_bounds__(256) void ln_transpose(
    const float* __restrict__ x0, const float* __restrict__ x1,
    const float* __restrict__ g0, const float* __restrict__ b0,
    const float* __restrict__ g1, const float* __restrict__ b1,
    u16* __restrict__ out0, u16* __restrict__ out1)
{
    int bid = blockIdx.x;
    int t = bid >> 7, b = (bid >> 6) & 1, p0 = (bid & 63) << 6;
    const float* x = t ? x1 : x0;
    const float* g = t ? g1 : g0;
    const float* bb = t ? b1 : b0;
    u16* out = t ? out1 : out0;

    int tid = threadIdx.x;
    int tx = tid & 63, ty = tid >> 6;
    const float* xb = x + (size_t)b * CD * HWD + p0 + tx;

    __shared__ float red[2][4][64];
    __shared__ u16 T[256][65];

    float s = 0.f, sq = 0.f;
    #pragma unroll 8
    for (int i = 0; i < 64; ++i) {
        float v = xb[(size_t)(ty * 64 + i) * HWD];
        s += v; sq += v * v;
    }
    red[0][ty][tx] = s; red[1][ty][tx] = sq;
    __syncthreads();
    float st  = red[0][0][tx] + red[0][1][tx] + red[0][2][tx] + red[0][3][tx];
    float sqt = red[1][0][tx] + red[1][1][tx] + red[1][2][tx] + red[1][3][tx];
    float mean = st * (1.f / 256.f);
    float var = sqt * (1.f / 256.f) - mean * mean;
    float rstd = rsqrtf(var + 1e-5f);

    #pragma unroll 8
    for (int i = 0; i < 64; ++i) {
        int c = ty * 64 + i;
        float v = (xb[(size_t)c * HWD] - mean) * rstd * g[c] + bb[c];
        T[c][tx] = f2b(v);
    }
    __syncthreads();

    int pr = tid >> 5, c0 = (tid & 31) * 8;
    #pragma unroll
    for (int pass = 0; pass < 8; ++pass) {
        int p = pass * 8 + pr;
        u16 tmp[8];
        #pragma unroll
        for (int j = 0; j < 8; ++j) tmp[j] = T[c0 + j][p];
        *(uint4*)&out[((size_t)b * HWD + p0 + p) * CD + c0] = *(const uint4*)tmp;
    }
}

// ---------------------------------------------------------------------------
// conv1x1 GEMM, bf16 [p][c] input, register-prefetched K-loop.
// grid (2 ctiles, 32 ptiles, 6 = mm*2+b), block 256.
// ---------------------------------------------------------------------------
__global__ __launch_bounds__(256) void qkv_gemm(
    const u16* __restrict__ xT, const u16* __restrict__ gT,
    const float* __restrict__ qw1, const float* __restrict__ qb1,
    const float* __restrict__ kw1, const float* __restrict__ kb1,
    const float* __restrict__ vw1, const float* __restrict__ vb1,
    u16* __restrict__ q1, u16* __restrict__ k1, u16* __restrict__ v1)
{
    int z = blockIdx.z;
    int mm = z >> 1, b = z & 1;
    const u16* X    = (mm == 0) ? xT : gT;
    const float* W  = (mm == 0) ? qw1 : (mm == 1) ? kw1 : vw1;
    const float* Bi = (mm == 0) ? qb1 : (mm == 1) ? kb1 : vb1;
    u16* Y          = (mm == 0) ? q1 : (mm == 1) ? k1 : v1;

    int n0 = blockIdx.x * 128;
    int p0 = blockIdx.y * 128;

    __shared__ u16 As[128][40];
    __shared__ u16 Bs[128][40];

    int tid = threadIdx.x;
    int lane = tid & 63, w = tid >> 6;
    int wm = w >> 1, wn = w & 1;
    int l15 = lane & 15, quad = lane >> 4;

    f32x4 acc[4][4];
    #pragma unroll
    for (int mi = 0; mi < 4; ++mi)
        #pragma unroll
        for (int nj = 0; nj < 4; ++nj)
            acc[mi][nj] = (f32x4){0.f, 0.f, 0.f, 0.f};

    const u16* Xb = X + (size_t)b * HWD * CD;

    int arow = tid >> 1, akh = (tid & 1) * 16;
    const u16* agp = Xb + (size_t)(p0 + arow) * CD + akh;
    const float* wgp = W + (size_t)(n0 + arow) * CD + akh;

    uint4 ra0 = *(const uint4*)(agp);
    uint4 ra1 = *(const uint4*)(agp + 8);
    float4 rw0 = ((const float4*)wgp)[0], rw1 = ((const float4*)wgp)[1];
    float4 rw2 = ((const float4*)wgp)[2], rw3 = ((const float4*)wgp)[3];

    for (int kt = 0; kt < 8; ++kt) {
        __syncthreads();
        *(uint4*)&As[arow][akh] = ra0;
        *(uint4*)&As[arow][akh + 8] = ra1;
        {
            uint4 qa, qb;
            qa.x = pk2(rw0.x, rw0.y); qa.y = pk2(rw0.z, rw0.w);
            qa.z = pk2(rw1.x, rw1.y); qa.w = pk2(rw1.z, rw1.w);
            qb.x = pk2(rw2.x, rw2.y); qb.y = pk2(rw2.z, rw2.w);
            qb.z = pk2(rw3.x, rw3.y); qb.w = pk2(rw3.z, rw3.w);
            *(uint4*)&Bs[arow][akh] = qa;
            *(uint4*)&Bs[arow][akh + 8] = qb;
        }
        if (kt < 7) {
            const u16* ag2 = agp + (kt + 1) * 32;
            const float* wg2 = wgp + (kt + 1) * 32;
            ra0 = *(const uint4*)(ag2);
            ra1 = *(const uint4*)(ag2 + 8);
            rw0 = ((const float4*)wg2)[0]; rw1 = ((const float4*)wg2)[1];
            rw2 = ((const float4*)wg2)[2]; rw3 = ((const float4*)wg2)[3];
        }
        __syncthreads();

        short8 af[4], bf[4];
        #pragma unroll
        for (int mi = 0; mi < 4; ++mi)
            af[mi] = *(const short8*)&As[wm * 64 + mi * 16 + l15][quad * 8];
        #pragma unroll
        for (int nj = 0; nj < 4; ++nj)
            bf[nj] = *(const short8*)&Bs[wn * 64 + nj * 16 + l15][quad * 8];
        #pragma unroll
        for (int mi = 0; mi < 4; ++mi)
            #pragma unroll
            for (int nj = 0; nj < 4; ++nj)
                acc[mi][nj] = __builtin_amdgcn_mfma_f32_16x16x32_bf16(
                    af[mi], bf[nj], acc[mi][nj], 0, 0, 0);
    }

    u16* Yb = Y + (size_t)b * HWD * CD;
    float bias[4];
    #pragma unroll
    for (int nj = 0; nj < 4; ++nj)
        bias[nj] = Bi[n0 + wn * 64 + nj * 16 + l15];
    #pragma unroll
    for (int mi = 0; mi < 4; ++mi) {
        #pragma unroll
        for (int r = 0; r < 4; ++r) {
            int p = p0 + wm * 64 + mi * 16 + quad * 4 + r;
            #pragma unroll
            for (int nj = 0; nj < 4; ++nj) {
                int ch = n0 + wn * 64 + nj * 16 + l15;
                Yb[(size_t)p * CD + ch] = f2b(acc[mi][nj][r] + bias[nj]);
            }
        }
    }
}

// ---------------------------------------------------------------------------
// depthwise 3x3 SAME + bias with row-register reuse (<=54 loads/thread,
// was 144); q scaled by 0.125*log2(e). Q,K out [b][n][c]; V out transposed.
// grid 1536, block 256 (lane = channel).
// ---------------------------------------------------------------------------
__global__ __launch_bounds__(256) void dwconv_nc(
    const u16* __restrict__ q1, const u16* __restrict__ k1, const u16* __restrict__ v1,
    const float* __restrict__ qw2, const float* __restrict__ qb2,
    const float* __restrict__ kw2, const float* __restrict__ kb2,
    const float* __restrict__ vw2, const float* __restrict__ vb2,
    u16* __restrict__ Q, u16* __restrict__ K, u16* __restrict__ Vt)
{
    int bid = blockIdx.x;
    int which = bid >> 9;
    int b = (bid >> 8) & 1;
    int p0 = (bid & 255) * 16;

    const u16* in = ((which == 0) ? q1 : (which == 1) ? k1 : v1) + (size_t)b * HWD * CD;
    const float* wsrc = (which == 0) ? qw2 : (which == 1) ? kw2 : vw2;
    const float* bsrc = (which == 0) ? qb2 : (which == 1) ? kb2 : vb2;
    float oscale = (which == 0) ? 0.18033688011112042f : 1.0f;

    int c = threadIdx.x;
    float w9[9];
    #pragma unroll
    for (int j = 0; j < 9; ++j) w9[j] = wsrc[c * 9 + j];
    float bias = bsrc[c];

    int h = p0 >> 6, w0 = p0 & 63;   // w0 in {0,16,32,48}, wave-uniform

    float accv[16];
    #pragma unroll
    for (int pi = 0; pi < 16; ++pi) accv[pi] = bias;

    #pragma unroll
    for (int dh = 0; dh < 3; ++dh) {
        int hh = h + dh - 1;
        if (hh < 0 || hh >= 64) continue;          // wave-uniform
        const u16* rp = in + ((size_t)hh * 64) * CD + c;
        float r[18];
        r[0] = (w0 > 0) ? b2f(rp[(size_t)(w0 - 1) * CD]) : 0.f;
        #pragma unroll
        for (int j = 1; j <= 16; ++j)
            r[j] = b2f(rp[(size_t)(w0 - 1 + j) * CD]);
        r[17] = (w0 < 48) ? b2f(rp[(size_t)(w0 + 16) * CD]) : 0.f;

        float wa = w9[dh * 3 + 0], wb = w9[dh * 3 + 1], wc = w9[dh * 3 + 2];
        #pragma unroll
        for (int pi = 0; pi < 16; ++pi)
            accv[pi] += wa * r[pi] + wb * r[pi + 1] + wc * r[pi + 2];
    }

    if (which == 2) {
        u32 w8[8];
        #pragma unroll
        for (int j = 0; j < 8; ++j) w8[j] = pk2(accv[2 * j], accv[2 * j + 1]);
        uint4* dst = (uint4*)(Vt + ((size_t)(b * CD + c)) * HWD + p0);
        dst[0] = make_uint4(w8[0], w8[1], w8[2], w8[3]);
        dst[1] = make_uint4(w8[4], w8[5], w8[6], w8[7]);
    } else {
        u16* out = ((which == 0) ? Q : K) + (size_t)b * HWD * CD;
        #pragma unroll
        for (int pi = 0; pi < 16; ++pi)
            out[(size_t)(p0 + pi) * CD + c] = f2b(accv[pi] * oscale);
    }
}

// ---------------------------------------------------------------------------
// Flash attention (S^T), BM=256 qrows/block (64/wave), key-split x4.
// Async double-buffered K/V staging (swizzled); Ps wave-private; one barrier
// per iter. bf16 unnormalized partials + fp32 psum, combined in out_gemm.
// grid (16 qtiles, 8 bh, 4 ks), block 256. LDS 64 KB -> 2 blocks/CU.
// ---------------------------------------------------------------------------
__global__ __launch_bounds__(256, 2) void attn_kernel(
    const u16* __restrict__ Q, const u16* __restrict__ K,
    const u16* __restrict__ Vt, u16* __restrict__ Opart,
    float* __restrict__ Psum)
{
    int qt = blockIdx.x;
    int bh = blockIdx.y;
    int ks = blockIdx.z;
    int b = bh >> 2, nh = bh & 3;

    __shared__ u16 Ks_[2][64 * 64];   // [key][d], granule-swizzled
    __shared__ u16 Vs_[2][64 * 64];   // [d][key], granule-swizzled
    __shared__ u16 Ps[256 * 64];      // [qrow][key], swizzled, wave-private rows

    int tid = threadIdx.x;
    int lane = tid & 63, w = tid >> 6;
    int l15 = lane & 15, quad = lane >> 4;
    int sw = l15 & 7;

    const u16* Qb = Q + ((size_t)b * HWD) * CD + nh * 64;
    const u16* Kb = K + ((size_t)b * HWD) * CD + nh * 64;
    const u16* Vb = Vt + ((size_t)bh * HDD) * HWD;

    // Q fragments (B operand of S^T): lane l15 = qrow; 4 row-tiles per wave
    short8 qf[4][2];
    #pragma unroll
    for (int qi = 0; qi < 4; ++qi) {
        const u16* qrow = Qb + (size_t)(qt * 256 + w * 64 + qi * 16 + l15) * CD + quad * 8;
        qf[qi][0] = *(const short8*)(qrow);
        qf[qi][1] = *(const short8*)(qrow + 32);
    }

    int rr = lane >> 3;
    int gseg = (lane & 7) ^ rr;
    const u16* kgb = Kb + (size_t)(ks * 1024 + w * 16 + rr) * CD + gseg * 8;
    const u16* vgb = Vb + (size_t)(w * 16 + rr) * HWD + ks * 1024 + gseg * 8;

    f32x4 acc_o[4][4];
    float psum[4] = {0.f, 0.f, 0.f, 0.f};
    #pragma unroll
    for (int qi = 0; qi < 4; ++qi)
        #pragma unroll
        for (int dj = 0; dj < 4; ++dj)
            acc_o[qi][dj] = (f32x4){0.f, 0.f, 0.f, 0.f};

    // prefetch tile 0 into buf 0
    #pragma unroll
    for (int j = 0; j < 2; ++j) {
        async16(kgb + (size_t)(j * 8) * CD, &Ks_[0][(w * 16 + j * 8) * 64]);
        async16(vgb + (size_t)(j * 8) * HWD, &Vs_[0][(w * 16 + j * 8) * 64]);
    }

    for (int it = 0; it < 16; ++it) {
        int cur = it & 1;
        __syncthreads();   // DMA for tile it drained; buf cur free of readers
        if (it + 1 < 16) {
            int nxt = cur ^ 1;
            #pragma unroll
            for (int j = 0; j < 2; ++j) {
                async16(kgb + (size_t)((it + 1) * 64 + j * 8) * CD,
                        &Ks_[nxt][(w * 16 + j * 8) * 64]);
                async16(vgb + (size_t)(j * 8) * HWD + (it + 1) * 64,
                        &Vs_[nxt][(w * 16 + j * 8) * 64]);
            }
        }

        // ---- K fragments ----
        short8 kf[4][2];
        #pragma unroll
        for (int nj = 0; nj < 4; ++nj)
            #pragma unroll
            for (int kk = 0; kk < 2; ++kk)
                kf[nj][kk] = *(const short8*)&Ks_[cur][(nj * 16 + l15) * 64 +
                                                      (((kk * 4 + quad) ^ sw) << 3)];

        // ---- per row-tile: S^T = K Q^T, exp2, pack -> Ps ----
        #pragma unroll
        for (int qi = 0; qi < 4; ++qi) {
            f32x4 st[4];
            #pragma unroll
            for (int nj = 0; nj < 4; ++nj) st[nj] = (f32x4){0.f, 0.f, 0.f, 0.f};
            #pragma unroll
            for (int kk = 0; kk < 2; ++kk)
                #pragma unroll
                for (int nj = 0; nj < 4; ++nj)
                    st[nj] = __builtin_amdgcn_mfma_f32_16x16x32_bf16(
                        kf[nj][kk], qf[qi][kk], st[nj], 0, 0, 0);

            int prow = (w * 64 + qi * 16 + l15) * 64;
            #pragma unroll
            for (int nj = 0; nj < 4; ++nj) {
                float e0 = fexp2(st[nj][0]);
                float e1 = fexp2(st[nj][1]);
                float e2 = fexp2(st[nj][2]);
                float e3 = fexp2(st[nj][3]);
                psum[qi] += (e0 + e1) + (e2 + e3);
                uint2 pw;
                pw.x = pk2r(e0, e1);
                pw.y = pk2r(e2, e3);
                int pcol = (((nj * 2 + (quad >> 1)) ^ sw) << 3) + (quad & 1) * 4;
                *(uint2*)&Ps[prow + pcol] = pw;
            }
        }

        // ---- V fragments (loaded late: only needed for PV) ----
        short8 vf[4][2];
        #pragma unroll
        for (int dj = 0; dj < 4; ++dj)
            #pragma unroll
            for (int kk = 0; kk < 2; ++kk)
                vf[dj][kk] = *(const short8*)&Vs_[cur][(dj * 16 + l15) * 64 +
                                                      (((kk * 4 + quad) ^ sw) << 3)];

        // ---- O += P V  (Ps rows wave-private; DS in-order) ----
        #pragma unroll
        for (int kk = 0; kk < 2; ++kk)
            #pragma unroll
            for (int qi = 0; qi < 4; ++qi) {
                short8 pf = *(const short8*)&Ps[(w * 64 + qi * 16 + l15) * 64 +
                                                (((kk * 4 + quad) ^ sw) << 3)];
                #pragma unroll
                for (int dj = 0; dj < 4; ++dj)
                    acc_o[qi][dj] = __builtin_amdgcn_mfma_f32_16x16x32_bf16(
                        pf, vf[dj][kk], acc_o[qi][dj], 0, 0, 0);
            }
    }

    // ---- write bf16 partials ----
    u16* Ob = Opart + (((size_t)ks * 8 + bh) * HWD) * HDD;
    #pragma unroll
    for (int qi = 0; qi < 4; ++qi)
        #pragma unroll
        for (int dj = 0; dj < 4; ++dj)
            #pragma unroll
            for (int r = 0; r < 4; ++r) {
                int n = qt * 256 + w * 64 + qi * 16 + quad * 4 + r;
                Ob[(size_t)n * HDD + dj * 16 + l15] = f2b(acc_o[qi][dj][r]);
            }

    float* Pb = Psum + ((size_t)ks * 8 + bh) * HWD + qt * 256 + w * 64;
    #pragma unroll
    for (int qi = 0; qi < 4; ++qi) {
        float s = psum[qi];
        s += __shfl_xor(s, 16);
        s += __shfl_xor(s, 32);
        if (quad == 0) Pb[qi * 16 + l15] = s;
    }
}

// ---------------------------------------------------------------------------
// out-proj GEMM + bias + residual, fp32 out; fuses the 4-way key-split
// combine: B-tile = (sum_s O_s) / (sum_s p_s), bf16 partial inputs.
// grid (64 ptiles, 2 ctiles, 2 b), block 256. Register-prefetched K-loop.
// ---------------------------------------------------------------------------
__global__ __launch_bounds__(256) void out_gemm(
    const float* __restrict__ W, const float* __restrict__ Bi,
    const u16* __restrict__ Opart, const float* __restrict__ Psum,
    const float* __restrict__ residual, float* __restrict__ out)
{
    int b = blockIdx.z;
    int m0 = blockIdx.y * 128;   // channels
    int n0 = blockIdx.x * 64;    // positions

    __shared__ u16 As[128][40];
    __shared__ u16 Bs[64][40];

    int tid = threadIdx.x;
    int lane = tid & 63, w = tid >> 6;
    int wm = w >> 1, wn = w & 1;
    int l15 = lane & 15, quad = lane >> 4;

    f32x4 acc[4][2];
    #pragma unroll
    for (int mi = 0; mi < 4; ++mi)
        #pragma unroll
        for (int nj = 0; nj < 2; ++nj)
            acc[mi][nj] = (f32x4){0.f, 0.f, 0.f, 0.f};

    int arow = tid >> 1, akh = (tid & 1) * 16;
    const float* wgp = W + (size_t)(m0 + arow) * CD + akh;
    int brow = tid >> 2, bseg = (tid & 3) * 8;
    int pn = n0 + brow;

    float4 rw0 = ((const float4*)wgp)[0], rw1 = ((const float4*)wgp)[1];
    float4 rw2 = ((const float4*)wgp)[2], rw3 = ((const float4*)wgp)[3];

    uint4 ro[4]; float rinv;
    {
        int c = bseg;
        int bh = b * 4 + (c >> 6), d0 = c & 63;
        float p = 0.f;
        #pragma unroll
        for (int s = 0; s < 4; ++s) {
            ro[s] = *(const uint4*)&Opart[(((size_t)s * 8 + bh) * HWD + pn) * HDD + d0];
            p += Psum[((size_t)s * 8 + bh) * HWD + pn];
        }
        rinv = 1.f / p;
    }

    for (int kt = 0; kt < 8; ++kt) {
        __syncthreads();
        {
            uint4 qa, qb;
            qa.x = pk2(rw0.x, rw0.y); qa.y = pk2(rw0.z, rw0.w);
            qa.z = pk2(rw1.x, rw1.y); qa.w = pk2(rw1.z, rw1.w);
            qb.x = pk2(rw2.x, rw2.y); qb.y = pk2(rw2.z, rw2.w);
            qb.z = pk2(rw3.x, rw3.y); qb.w = pk2(rw3.z, rw3.w);
            *(uint4*)&As[arow][akh] = qa;
            *(uint4*)&As[arow][akh + 8] = qb;
        }
        {
            float v[8];
            #pragma unroll
            for (int j = 0; j < 8; ++j) v[j] = 0.f;
            #pragma unroll
            for (int s = 0; s < 4; ++s) {
                u16 t[8];
                *(uint4*)t = ro[s];
                #pragma unroll
                for (int j = 0; j < 8; ++j) v[j] += b2f(t[j]);
            }
            uint4 bb;
            bb.x = pk2(v[0] * rinv, v[1] * rinv);
            bb.y = pk2(v[2] * rinv, v[3] * rinv);
            bb.z = pk2(v[4] * rinv, v[5] * rinv);
            bb.w = pk2(v[6] * rinv, v[7] * rinv);
            *(uint4*)&Bs[brow][bseg] = bb;
        }
        if (kt < 7) {
            const float* wg2 = wgp + (kt + 1) * 32;
            rw0 = ((const float4*)wg2)[0]; rw1 = ((const float4*)wg2)[1];
            rw2 = ((const float4*)wg2)[2]; rw3 = ((const float4*)wg2)[3];
            int c = (kt + 1) * 32 + bseg;
            int bh = b * 4 + (c >> 6), d0 = c & 63;
            float p = 0.f;
            #pragma unroll
            for (int s = 0; s < 4; ++s) {
                ro[s] = *(const uint4*)&Opart[(((size_t)s * 8 + bh) * HWD + pn) * HDD + d0];
                p += Psum[((size_t)s * 8 + bh) * HWD + pn];
            }
            rinv = 1.f / p;
        }
        __syncthreads();

        short8 af[4], bf[2];
        #pragma unroll
        for (int mi = 0; mi < 4; ++mi)
            af[mi] = *(const short8*)&As[wm * 64 + mi * 16 + l15][quad * 8];
        #pragma unroll
        for (int nj = 0; nj < 2; ++nj)
            bf[nj] = *(const short8*)&Bs[wn * 32 + nj * 16 + l15][quad * 8];
        #pragma unroll
        for (int mi = 0; mi < 4; ++mi)
            #pragma unroll
            for (int nj = 0; nj < 2; ++nj)
                acc[mi][nj] = __builtin_amdgcn_mfma_f32_16x16x32_bf16(
                    af[mi], bf[nj], acc[mi][nj], 0, 0, 0);
    }

    #pragma unroll
    for (int mi = 0; mi < 4; ++mi) {
        int mb = m0 + wm * 64 + mi * 16 + quad * 4;
        #pragma unroll
        for (int r = 0; r < 4; ++r) {
            float bias = Bi[mb + r];
            const float* res = residual + (size_t)(b * CD + mb + r) * HWD;
            float* o = out + (size_t)(b * CD + mb + r) * HWD;
            #pragma unroll
            for (int nj = 0; nj < 2; ++nj) {
                int n = n0 + wn * 32 + nj * 16 + l15;
                o[n] = acc[mi][nj][r] + bias + res[n];
            }
        }
    }
}

extern "C" void kernel_launch(void* const* d_in, const int* in_sizes, int n_in,
                              void* d_out, int out_size, void* d_ws, size_t ws_size,
                              hipStream_t stream) {
    (void)in_sizes; (void)n_in; (void)out_size; (void)ws_size;

    const float* image = (const float*)d_in[0];
    const float* guide = (const float*)d_in[1];
    const float* ln1_g = (const float*)d_in[2];
    const float* ln1_b = (const float*)d_in[3];
    const float* ln2_g = (const float*)d_in[4];
    const float* ln2_b = (const float*)d_in[5];
    const float* qw1 = (const float*)d_in[6];
    const float* qb1 = (const float*)d_in[7];
    const float* qw2 = (const float*)d_in[8];
    const float* qb2 = (const float*)d_in[9];
    const float* kw1 = (const float*)d_in[10];
    const float* kb1 = (const float*)d_in[11];
    const float* kw2 = (const float*)d_in[12];
    const float* kb2 = (const float*)d_in[13];
    const float* vw1 = (const float*)d_in[14];
    const float* vb1 = (const float*)d_in[15];
    const float* vw2 = (const float*)d_in[16];
    const float* vb2 = (const float*)d_in[17];
    const float* ow  = (const float*)d_in[18];
    const float* ob  = (const float*)d_in[19];
    float* out = (float*)d_out;

    char* ws = (char*)d_ws;
    u16* xT    = (u16*)(ws + (size_t)0  * (1 << 20));
    u16* gT    = (u16*)(ws + (size_t)4  * (1 << 20));
    u16* q1    = (u16*)(ws + (size_t)8  * (1 << 20));
    u16* k1    = (u16*)(ws + (size_t)12 * (1 << 20));
    u16* v1    = (u16*)(ws + (size_t)16 * (1 << 20));
    u16* Qh    = (u16*)(ws + (size_t)20 * (1 << 20));
    u16* Kh    = (u16*)(ws + (size_t)24 * (1 << 20));
    u16* Vt    = (u16*)(ws + (size_t)28 * (1 << 20));
    // attn partials overlay dead phase-1 buffers (xT..v1 region, 0..20 MB):
    // Opart bf16 = 32 slots * 4096 * 64 * 2B = 16.78 MB at 0; Psum 0.5 MB at 18 MB
    u16*   Opart = (u16*)(ws + (size_t)0  * (1 << 20));
    float* Psum  = (float*)(ws + (size_t)18 * (1 << 20));

    ln_transpose<<<dim3(256), dim3(256), 0, stream>>>(
        image, guide, ln1_g, ln1_b, ln2_g, ln2_b, xT, gT);

    qkv_gemm<<<dim3(2, 32, 6), dim3(256), 0, stream>>>(
        xT, gT, qw1, qb1, kw1, kb1, vw1, vb1, q1, k1, v1);

    dwconv_nc<<<dim3(1536), dim3(256), 0, stream>>>(
        q1, k1, v1, qw2, qb2, kw2, kb2, vw2, vb2, Qh, Kh, Vt);

    attn_kernel<<<dim3(16, 8, 4), dim3(256), 0, stream>>>(Qh, Kh, Vt, Opart, Psum);

    out_gemm<<<dim3(64, 2, 2), dim3(256), 0, stream>>>(
        ow, ob, Opart, Psum, image, out);
}

// Round 9
// 182.834 us; speedup vs baseline: 1.4182x; 1.0334x over previous
//
#include <hip/hip_runtime.h>
#include <cstdint>
#include <cstddef>

typedef unsigned short u16;
typedef unsigned int u32;
typedef __attribute__((ext_vector_type(8))) short short8;
typedef __attribute__((ext_vector_type(4))) float f32x4;

#define CD 256
#define HWD 4096
#define NHD 4
#define HDD 64

static __device__ __forceinline__ u16 f2b(float f) {
    u32 u = __builtin_bit_cast(u32, f);
    return (u16)((u + 0x7fffu + ((u >> 16) & 1u)) >> 16);
}
static __device__ __forceinline__ float b2f(u16 h) {
    return __builtin_bit_cast(float, (u32)h << 16);
}
static __device__ __forceinline__ u32 pk2(float a, float b) {
    return (u32)f2b(a) | ((u32)f2b(b) << 16);
}
// cheap round-half-up bf16 pack (positive values; bias cancels in softmax ratio)
static __device__ __forceinline__ u32 pk2r(float a, float b) {
    u32 ua = __builtin_bit_cast(u32, a) + 0x8000u;
    u32 ub = __builtin_bit_cast(u32, b) + 0x8000u;
    return (ua >> 16) | (ub & 0xffff0000u);
}
static __device__ __forceinline__ float fexp2(float x) {
#if __has_builtin(__builtin_amdgcn_exp2f)
    return __builtin_amdgcn_exp2f(x);
#else
    return __expf(x * 0.69314718056f);
#endif
}
// async global->LDS DMA, 16 B per lane; LDS dest = wave-uniform base + lane*16
static __device__ __forceinline__ void async16(const void* g, void* l) {
    __builtin_amdgcn_global_load_lds(
        (const __attribute__((address_space(1))) unsigned int*)g,
        (__attribute__((address_space(3))) unsigned int*)l,
        16, 0, 0);
}

// ---------------------------------------------------------------------------
// LayerNorm over C + transpose to bf16 [b][p][c]. 32-pos chunks for TLP.
// grid 512: bid>>8 = tensor, (bid>>7)&1 = b, (bid&127)*32 = p0. block 256.
// ---------------------------------------------------------------------------
__global__ __launch_bounds__(256) void ln_transpose(
    const float* __restrict__ x0, const float* __restrict__ x1,
    const float* __restrict__ g0, const float* __restrict__ b0,
    const float* __restrict__ g1, const float* __restrict__ b1,
    u16* __restrict__ out0, u16* __restrict__ out1)
{
    int bid = blockIdx.x;
    int t = bid >> 8, b = (bid >> 7) & 1, p0 = (bid & 127) << 5;
    const float* x = t ? x1 : x0;
    const float* g = t ? g1 : g0;
    const float* bb = t ? b1 : b0;
    u16* out = t ? out1 : out0;

    int tid = threadIdx.x;
    int tx = tid & 31, ty = tid >> 5;   // ty 0..7 = channel slice
    const float* xb = x + (size_t)b * CD * HWD + p0 + tx;

    __shared__ float red[2][8][32];
    __shared__ u16 T[256][33];

    float s = 0.f, sq = 0.f;
    #pragma unroll 8
    for (int i = 0; i < 32; ++i) {
        float v = xb[(size_t)(ty * 32 + i) * HWD];
        s += v; sq += v * v;
    }
    red[0][ty][tx] = s; red[1][ty][tx] = sq;
    __syncthreads();
    float st = 0.f, sqt = 0.f;
    #pragma unroll
    for (int j = 0; j < 8; ++j) { st += red[0][j][tx]; sqt += red[1][j][tx]; }
    float mean = st * (1.f / 256.f);
    float var = sqt * (1.f / 256.f) - mean * mean;
    float rstd = rsqrtf(var + 1e-5f);

    #pragma unroll 8
    for (int i = 0; i < 32; ++i) {
        int c = ty * 32 + i;
        float v = (xb[(size_t)c * HWD] - mean) * rstd * g[c] + bb[c];
        T[c][tx] = f2b(v);
    }
    __syncthreads();

    #pragma unroll
    for (int pass = 0; pass < 4; ++pass) {
        int idx = pass * 256 + tid;
        int p = idx >> 5, cs = (idx & 31) * 8;
        u16 tmp[8];
        #pragma unroll
        for (int j = 0; j < 8; ++j) tmp[j] = T[cs + j][p];
        *(uint4*)&out[((size_t)b * HWD + p0 + p) * CD + cs] = *(const uint4*)tmp;
    }
}

// ---------------------------------------------------------------------------
// conv1x1 GEMM, bf16 [p][c] input, register-prefetched K-loop.
// Tile 64 pos x 128 ch. grid (2 ctiles, 64 ptiles, 6 = mm*2+b), block 256.
// 768 blocks -> 3 blocks/CU for latency hiding.
// ---------------------------------------------------------------------------
__global__ __launch_bounds__(256) void qkv_gemm(
    const u16* __restrict__ xT, const u16* __restrict__ gT,
    const float* __restrict__ qw1, const float* __restrict__ qb1,
    const float* __restrict__ kw1, const float* __restrict__ kb1,
    const float* __restrict__ vw1, const float* __restrict__ vb1,
    u16* __restrict__ q1, u16* __restrict__ k1, u16* __restrict__ v1)
{
    int z = blockIdx.z;
    int mm = z >> 1, b = z & 1;
    const u16* X    = (mm == 0) ? xT : gT;
    const float* W  = (mm == 0) ? qw1 : (mm == 1) ? kw1 : vw1;
    const float* Bi = (mm == 0) ? qb1 : (mm == 1) ? kb1 : vb1;
    u16* Y          = (mm == 0) ? q1 : (mm == 1) ? k1 : v1;

    int n0 = blockIdx.x * 128;   // channel tile
    int p0 = blockIdx.y * 64;    // position tile

    __shared__ u16 As[64][40];
    __shared__ u16 Bs[128][40];

    int tid = threadIdx.x;
    int lane = tid & 63, w = tid >> 6;
    int wm = w >> 1, wn = w & 1;
    int l15 = lane & 15, quad = lane >> 4;

    f32x4 acc[2][4];
    #pragma unroll
    for (int mi = 0; mi < 2; ++mi)
        #pragma unroll
        for (int nj = 0; nj < 4; ++nj)
            acc[mi][nj] = (f32x4){0.f, 0.f, 0.f, 0.f};

    const u16* Xb = X + (size_t)b * HWD * CD;

    int arow = tid >> 2, aseg = (tid & 3) * 8;
    const u16* agp = Xb + (size_t)(p0 + arow) * CD + aseg;
    int brow = tid >> 1, bkh = (tid & 1) * 16;
    const float* wgp = W + (size_t)(n0 + brow) * CD + bkh;

    uint4 ra = *(const uint4*)(agp);
    float4 rw0 = ((const float4*)wgp)[0], rw1 = ((const float4*)wgp)[1];
    float4 rw2 = ((const float4*)wgp)[2], rw3 = ((const float4*)wgp)[3];

    for (int kt = 0; kt < 8; ++kt) {
        __syncthreads();
        *(uint4*)&As[arow][aseg] = ra;
        {
            uint4 qa, qb;
            qa.x = pk2(rw0.x, rw0.y); qa.y = pk2(rw0.z, rw0.w);
            qa.z = pk2(rw1.x, rw1.y); qa.w = pk2(rw1.z, rw1.w);
            qb.x = pk2(rw2.x, rw2.y); qb.y = pk2(rw2.z, rw2.w);
            qb.z = pk2(rw3.x, rw3.y); qb.w = pk2(rw3.z, rw3.w);
            *(uint4*)&Bs[brow][bkh] = qa;
            *(uint4*)&Bs[brow][bkh + 8] = qb;
        }
        if (kt < 7) {
            ra = *(const uint4*)(agp + (kt + 1) * 32);
            const float* wg2 = wgp + (kt + 1) * 32;
            rw0 = ((const float4*)wg2)[0]; rw1 = ((const float4*)wg2)[1];
            rw2 = ((const float4*)wg2)[2]; rw3 = ((const float4*)wg2)[3];
        }
        __syncthreads();

        short8 af[2], bf[4];
        #pragma unroll
        for (int mi = 0; mi < 2; ++mi)
            af[mi] = *(const short8*)&As[wm * 32 + mi * 16 + l15][quad * 8];
        #pragma unroll
        for (int nj = 0; nj < 4; ++nj)
            bf[nj] = *(const short8*)&Bs[wn * 64 + nj * 16 + l15][quad * 8];
        #pragma unroll
        for (int mi = 0; mi < 2; ++mi)
            #pragma unroll
            for (int nj = 0; nj < 4; ++nj)
                acc[mi][nj] = __builtin_amdgcn_mfma_f32_16x16x32_bf16(
                    af[mi], bf[nj], acc[mi][nj], 0, 0, 0);
    }

    u16* Yb = Y + (size_t)b * HWD * CD;
    float bias[4];
    #pragma unroll
    for (int nj = 0; nj < 4; ++nj)
        bias[nj] = Bi[n0 + wn * 64 + nj * 16 + l15];
    #pragma unroll
    for (int mi = 0; mi < 2; ++mi) {
        #pragma unroll
        for (int r = 0; r < 4; ++r) {
            int p = p0 + wm * 32 + mi * 16 + quad * 4 + r;
            #pragma unroll
            for (int nj = 0; nj < 4; ++nj) {
                int ch = n0 + wn * 64 + nj * 16 + l15;
                Yb[(size_t)p * CD + ch] = f2b(acc[mi][nj][r] + bias[nj]);
            }
        }
    }
}

// ---------------------------------------------------------------------------
// depthwise 3x3 SAME + bias with row-register reuse; q scaled 0.125*log2(e).
// Q,K out [b][n][c]; V out transposed. grid 1536, block 256 (lane = channel).
// ---------------------------------------------------------------------------
__global__ __launch_bounds__(256) void dwconv_nc(
    const u16* __restrict__ q1, const u16* __restrict__ k1, const u16* __restrict__ v1,
    const float* __restrict__ qw2, const float* __restrict__ qb2,
    const float* __restrict__ kw2, const float* __restrict__ kb2,
    const float* __restrict__ vw2, const float* __restrict__ vb2,
    u16* __restrict__ Q, u16* __restrict__ K, u16* __restrict__ Vt)
{
    int bid = blockIdx.x;
    int which = bid >> 9;
    int b = (bid >> 8) & 1;
    int p0 = (bid & 255) * 16;

    const u16* in = ((which == 0) ? q1 : (which == 1) ? k1 : v1) + (size_t)b * HWD * CD;
    const float* wsrc = (which == 0) ? qw2 : (which == 1) ? kw2 : vw2;
    const float* bsrc = (which == 0) ? qb2 : (which == 1) ? kb2 : vb2;
    float oscale = (which == 0) ? 0.18033688011112042f : 1.0f;

    int c = threadIdx.x;
    float w9[9];
    #pragma unroll
    for (int j = 0; j < 9; ++j) w9[j] = wsrc[c * 9 + j];
    float bias = bsrc[c];

    int h = p0 >> 6, w0 = p0 & 63;   // w0 in {0,16,32,48}, wave-uniform

    float accv[16];
    #pragma unroll
    for (int pi = 0; pi < 16; ++pi) accv[pi] = bias;

    #pragma unroll
    for (int dh = 0; dh < 3; ++dh) {
        int hh = h + dh - 1;
        if (hh < 0 || hh >= 64) continue;          // wave-uniform
        const u16* rp = in + ((size_t)hh * 64) * CD + c;
        float r[18];
        r[0] = (w0 > 0) ? b2f(rp[(size_t)(w0 - 1) * CD]) : 0.f;
        #pragma unroll
        for (int j = 1; j <= 16; ++j)
            r[j] = b2f(rp[(size_t)(w0 - 1 + j) * CD]);
        r[17] = (w0 < 48) ? b2f(rp[(size_t)(w0 + 16) * CD]) : 0.f;

        float wa = w9[dh * 3 + 0], wb = w9[dh * 3 + 1], wc = w9[dh * 3 + 2];
        #pragma unroll
        for (int pi = 0; pi < 16; ++pi)
            accv[pi] += wa * r[pi] + wb * r[pi + 1] + wc * r[pi + 2];
    }

    if (which == 2) {
        u32 w8[8];
        #pragma unroll
        for (int j = 0; j < 8; ++j) w8[j] = pk2(accv[2 * j], accv[2 * j + 1]);
        uint4* dst = (uint4*)(Vt + ((size_t)(b * CD + c)) * HWD + p0);
        dst[0] = make_uint4(w8[0], w8[1], w8[2], w8[3]);
        dst[1] = make_uint4(w8[4], w8[5], w8[6], w8[7]);
    } else {
        u16* out = ((which == 0) ? Q : K) + (size_t)b * HWD * CD;
        #pragma unroll
        for (int pi = 0; pi < 16; ++pi)
            out[(size_t)(p0 + pi) * CD + c] = f2b(accv[pi] * oscale);
    }
}

// ---------------------------------------------------------------------------
// Flash attention (S^T), BM=256 qrows/block (64/wave), key-split x4.
// Async double-buffered K/V staging (swizzled); Ps wave-private; one barrier
// per iter. bf16 unnormalized partials + fp32 psum, combined in out_gemm.
// grid (16 qtiles, 8 bh, 4 ks), block 256. LDS 64 KB -> 2 blocks/CU.
// ---------------------------------------------------------------------------
__global__ __launch_bounds__(256, 2) void attn_kernel(
    const u16* __restrict__ Q, const u16* __restrict__ K,
    const u16* __restrict__ Vt, u16* __restrict__ Opart,
    float* __restrict__ Psum)
{
    int qt = blockIdx.x;
    int bh = blockIdx.y;
    int ks = blockIdx.z;
    int b = bh >> 2, nh = bh & 3;

    __shared__ u16 Ks_[2][64 * 64];   // [key][d], granule-swizzled
    __shared__ u16 Vs_[2][64 * 64];   // [d][key], granule-swizzled
    __shared__ u16 Ps[256 * 64];      // [qrow][key], swizzled, wave-private rows

    int tid = threadIdx.x;
    int lane = tid & 63, w = tid >> 6;
    int l15 = lane & 15, quad = lane >> 4;
    int sw = l15 & 7;

    const u16* Qb = Q + ((size_t)b * HWD) * CD + nh * 64;
    const u16* Kb = K + ((size_t)b * HWD) * CD + nh * 64;
    const u16* Vb = Vt + ((size_t)bh * HDD) * HWD;

    // Q fragments (B operand of S^T): lane l15 = qrow; 4 row-tiles per wave
    short8 qf[4][2];
    #pragma unroll
    for (int qi = 0; qi < 4; ++qi) {
        const u16* qrow = Qb + (size_t)(qt * 256 + w * 64 + qi * 16 + l15) * CD + quad * 8;
        qf[qi][0] = *(const short8*)(qrow);
        qf[qi][1] = *(const short8*)(qrow + 32);
    }

    int rr = lane >> 3;
    int gseg = (lane & 7) ^ rr;
    const u16* kgb = Kb + (size_t)(ks * 1024 + w * 16 + rr) * CD + gseg * 8;
    const u16* vgb = Vb + (size_t)(w * 16 + rr) * HWD + ks * 1024 + gseg * 8;

    f32x4 acc_o[4][4];
    float psum[4] = {0.f, 0.f, 0.f, 0.f};
    #pragma unroll
    for (int qi = 0; qi < 4; ++qi)
        #pragma unroll
        for (int dj = 0; dj < 4; ++dj)
            acc_o[qi][dj] = (f32x4){0.f, 0.f, 0.f, 0.f};

    // prefetch tile 0 into buf 0
    #pragma unroll
    for (int j = 0; j < 2; ++j) {
        async16(kgb + (size_t)(j * 8) * CD, &Ks_[0][(w * 16 + j * 8) * 64]);
        async16(vgb + (size_t)(j * 8) * HWD, &Vs_[0][(w * 16 + j * 8) * 64]);
    }

    for (int it = 0; it < 16; ++it) {
        int cur = it & 1;
        __syncthreads();   // DMA for tile it drained; buf cur free of readers
        if (it + 1 < 16) {
            int nxt = cur ^ 1;
            #pragma unroll
            for (int j = 0; j < 2; ++j) {
                async16(kgb + (size_t)((it + 1) * 64 + j * 8) * CD,
                        &Ks_[nxt][(w * 16 + j * 8) * 64]);
                async16(vgb + (size_t)(j * 8) * HWD + (it + 1) * 64,
                        &Vs_[nxt][(w * 16 + j * 8) * 64]);
            }
        }

        // ---- K fragments ----
        short8 kf[4][2];
        #pragma unroll
        for (int nj = 0; nj < 4; ++nj)
            #pragma unroll
            for (int kk = 0; kk < 2; ++kk)
                kf[nj][kk] = *(const short8*)&Ks_[cur][(nj * 16 + l15) * 64 +
                                                      (((kk * 4 + quad) ^ sw) << 3)];

        // ---- per row-tile: S^T = K Q^T, exp2, pack -> Ps ----
        #pragma unroll
        for (int qi = 0; qi < 4; ++qi) {
            f32x4 st[4];
            #pragma unroll
            for (int nj = 0; nj < 4; ++nj) st[nj] = (f32x4){0.f, 0.f, 0.f, 0.f};
            #pragma unroll
            for (int kk = 0; kk < 2; ++kk)
                #pragma unroll
                for (int nj = 0; nj < 4; ++nj)
                    st[nj] = __builtin_amdgcn_mfma_f32_16x16x32_bf16(
                        kf[nj][kk], qf[qi][kk], st[nj], 0, 0, 0);

            int prow = (w * 64 + qi * 16 + l15) * 64;
            #pragma unroll
            for (int nj = 0; nj < 4; ++nj) {
                float e0 = fexp2(st[nj][0]);
                float e1 = fexp2(st[nj][1]);
                float e2 = fexp2(st[nj][2]);
                float e3 = fexp2(st[nj][3]);
                psum[qi] += (e0 + e1) + (e2 + e3);
                uint2 pw;
                pw.x = pk2r(e0, e1);
                pw.y = pk2r(e2, e3);
                int pcol = (((nj * 2 + (quad >> 1)) ^ sw) << 3) + (quad & 1) * 4;
                *(uint2*)&Ps[prow + pcol] = pw;
            }
        }

        // ---- V fragments ----
        short8 vf[4][2];
        #pragma unroll
        for (int dj = 0; dj < 4; ++dj)
            #pragma unroll
            for (int kk = 0; kk < 2; ++kk)
                vf[dj][kk] = *(const short8*)&Vs_[cur][(dj * 16 + l15) * 64 +
                                                      (((kk * 4 + quad) ^ sw) << 3)];

        // ---- O += P V  (Ps rows wave-private; DS in-order) ----
        #pragma unroll
        for (int kk = 0; kk < 2; ++kk)
            #pragma unroll
            for (int qi = 0; qi < 4; ++qi) {
                short8 pf = *(const short8*)&Ps[(w * 64 + qi * 16 + l15) * 64 +
                                                (((kk * 4 + quad) ^ sw) << 3)];
                #pragma unroll
                for (int dj = 0; dj < 4; ++dj)
                    acc_o[qi][dj] = __builtin_amdgcn_mfma_f32_16x16x32_bf16(
                        pf, vf[dj][kk], acc_o[qi][dj], 0, 0, 0);
            }
    }

    // ---- write bf16 partials ----
    u16* Ob = Opart + (((size_t)ks * 8 + bh) * HWD) * HDD;
    #pragma unroll
    for (int qi = 0; qi < 4; ++qi)
        #pragma unroll
        for (int dj = 0; dj < 4; ++dj)
            #pragma unroll
            for (int r = 0; r < 4; ++r) {
                int n = qt * 256 + w * 64 + qi * 16 + quad * 4 + r;
                Ob[(size_t)n * HDD + dj * 16 + l15] = f2b(acc_o[qi][dj][r]);
            }

    float* Pb = Psum + ((size_t)ks * 8 + bh) * HWD + qt * 256 + w * 64;
    #pragma unroll
    for (int qi = 0; qi < 4; ++qi) {
        float s = psum[qi];
        s += __shfl_xor(s, 16);
        s += __shfl_xor(s, 32);
        if (quad == 0) Pb[qi * 16 + l15] = s;
    }
}

// ---------------------------------------------------------------------------
// out-proj GEMM + bias + residual, fp32 out; fuses the 4-way key-split
// combine. Tile 64 ch x 64 pos. grid (64 ptiles, 4 ctiles, 2 b) = 512 blocks.
// ---------------------------------------------------------------------------
__global__ __launch_bounds__(256) void out_gemm(
    const float* __restrict__ W, const float* __restrict__ Bi,
    const u16* __restrict__ Opart, const float* __restrict__ Psum,
    const float* __restrict__ residual, float* __restrict__ out)
{
    int b = blockIdx.z;
    int m0 = blockIdx.y * 64;    // channels
    int n0 = blockIdx.x * 64;    // positions

    __shared__ u16 As[64][40];
    __shared__ u16 Bs[64][40];

    int tid = threadIdx.x;
    int lane = tid & 63, w = tid >> 6;
    int wm = w >> 1, wn = w & 1;
    int l15 = lane & 15, quad = lane >> 4;

    f32x4 acc[2][2];
    #pragma unroll
    for (int mi = 0; mi < 2; ++mi)
        #pragma unroll
        for (int nj = 0; nj < 2; ++nj)
            acc[mi][nj] = (f32x4){0.f, 0.f, 0.f, 0.f};

    int arow = tid >> 2, aseg = (tid & 3) * 8;
    const float* wgp = W + (size_t)(m0 + arow) * CD + aseg;
    int brow = tid >> 2, bseg = (tid & 3) * 8;
    int pn = n0 + brow;

    float4 rw0 = ((const float4*)wgp)[0], rw1 = ((const float4*)wgp)[1];

    uint4 ro[4]; float rinv;
    {
        int c = bseg;
        int bh = b * 4 + (c >> 6), d0 = c & 63;
        float p = 0.f;
        #pragma unroll
        for (int s = 0; s < 4; ++s) {
            ro[s] = *(const uint4*)&Opart[(((size_t)s * 8 + bh) * HWD + pn) * HDD + d0];
            p += Psum[((size_t)s * 8 + bh) * HWD + pn];
        }
        rinv = 1.f / p;
    }

    for (int kt = 0; kt < 8; ++kt) {
        __syncthreads();
        {
            uint4 qa;
            qa.x = pk2(rw0.x, rw0.y); qa.y = pk2(rw0.z, rw0.w);
            qa.z = pk2(rw1.x, rw1.y); qa.w = pk2(rw1.z, rw1.w);
            *(uint4*)&As[arow][aseg] = qa;
        }
        {
            float v[8];
            #pragma unroll
            for (int j = 0; j < 8; ++j) v[j] = 0.f;
            #pragma unroll
            for (int s = 0; s < 4; ++s) {
                u16 t[8];
                *(uint4*)t = ro[s];
                #pragma unroll
                for (int j = 0; j < 8; ++j) v[j] += b2f(t[j]);
            }
            uint4 bb;
            bb.x = pk2(v[0] * rinv, v[1] * rinv);
            bb.y = pk2(v[2] * rinv, v[3] * rinv);
            bb.z = pk2(v[4] * rinv, v[5] * rinv);
            bb.w = pk2(v[6] * rinv, v[7] * rinv);
            *(uint4*)&Bs[brow][bseg] = bb;
        }
        if (kt < 7) {
            const float* wg2 = wgp + (kt + 1) * 32;
            rw0 = ((const float4*)wg2)[0]; rw1 = ((const float4*)wg2)[1];
            int c = (kt + 1) * 32 + bseg;
            int bh = b * 4 + (c >> 6), d0 = c & 63;
            float p = 0.f;
            #pragma unroll
            for (int s = 0; s < 4; ++s) {
                ro[s] = *(const uint4*)&Opart[(((size_t)s * 8 + bh) * HWD + pn) * HDD + d0];
                p += Psum[((size_t)s * 8 + bh) * HWD + pn];
            }
            rinv = 1.f / p;
        }
        __syncthreads();

        short8 af[2], bf[2];
        #pragma unroll
        for (int mi = 0; mi < 2; ++mi)
            af[mi] = *(const short8*)&As[wm * 32 + mi * 16 + l15][quad * 8];
        #pragma unroll
        for (int nj = 0; nj < 2; ++nj)
            bf[nj] = *(const short8*)&Bs[wn * 32 + nj * 16 + l15][quad * 8];
        #pragma unroll
        for (int mi = 0; mi < 2; ++mi)
            #pragma unroll
            for (int nj = 0; nj < 2; ++nj)
                acc[mi][nj] = __builtin_amdgcn_mfma_f32_16x16x32_bf16(
                    af[mi], bf[nj], acc[mi][nj], 0, 0, 0);
    }

    #pragma unroll
    for (int mi = 0; mi < 2; ++mi) {
        int mb = m0 + wm * 32 + mi * 16 + quad * 4;
        #pragma unroll
        for (int r = 0; r < 4; ++r) {
            float bias = Bi[mb + r];
            const float* res = residual + (size_t)(b * CD + mb + r) * HWD;
            float* o = out + (size_t)(b * CD + mb + r) * HWD;
            #pragma unroll
            for (int nj = 0; nj < 2; ++nj) {
                int n = n0 + wn * 32 + nj * 16 + l15;
                o[n] = acc[mi][nj][r] + bias + res[n];
            }
        }
    }
}

extern "C" void kernel_launch(void* const* d_in, const int* in_sizes, int n_in,
                              void* d_out, int out_size, void* d_ws, size_t ws_size,
                              hipStream_t stream) {
    (void)in_sizes; (void)n_in; (void)out_size; (void)ws_size;

    const float* image = (const float*)d_in[0];
    const float* guide = (const float*)d_in[1];
    const float* ln1_g = (const float*)d_in[2];
    const float* ln1_b = (const float*)d_in[3];
    const float* ln2_g = (const float*)d_in[4];
    const float* ln2_b = (const float*)d_in[5];
    const float* qw1 = (const float*)d_in[6];
    const float* qb1 = (const float*)d_in[7];
    const float* qw2 = (const float*)d_in[8];
    const float* qb2 = (const float*)d_in[9];
    const float* kw1 = (const float*)d_in[10];
    const float* kb1 = (const float*)d_in[11];
    const float* kw2 = (const float*)d_in[12];
    const float* kb2 = (const float*)d_in[13];
    const float* vw1 = (const float*)d_in[14];
    const float* vb1 = (const float*)d_in[15];
    const float* vw2 = (const float*)d_in[16];
    const float* vb2 = (const float*)d_in[17];
    const float* ow  = (const float*)d_in[18];
    const float* ob  = (const float*)d_in[19];
    float* out = (float*)d_out;

    char* ws = (char*)d_ws;
    u16* xT    = (u16*)(ws + (size_t)0  * (1 << 20));
    u16* gT    = (u16*)(ws + (size_t)4  * (1 << 20));
    u16* q1    = (u16*)(ws + (size_t)8  * (1 << 20));
    u16* k1    = (u16*)(ws + (size_t)12 * (1 << 20));
    u16* v1    = (u16*)(ws + (size_t)16 * (1 << 20));
    u16* Qh    = (u16*)(ws + (size_t)20 * (1 << 20));
    u16* Kh    = (u16*)(ws + (size_t)24 * (1 << 20));
    u16* Vt    = (u16*)(ws + (size_t)28 * (1 << 20));
    // attn partials overlay dead phase-1 buffers (xT..v1 region, 0..20 MB)
    u16*   Opart = (u16*)(ws + (size_t)0  * (1 << 20));
    float* Psum  = (float*)(ws + (size_t)18 * (1 << 20));

    ln_transpose<<<dim3(512), dim3(256), 0, stream>>>(
        image, guide, ln1_g, ln1_b, ln2_g, ln2_b, xT, gT);

    qkv_gemm<<<dim3(2, 64, 6), dim3(256), 0, stream>>>(
        xT, gT, qw1, qb1, kw1, kb1, vw1, vb1, q1, k1, v1);

    dwconv_nc<<<dim3(1536), dim3(256), 0, stream>>>(
        q1, k1, v1, qw2, qb2, kw2, kb2, vw2, vb2, Qh, Kh, Vt);

    attn_kernel<<<dim3(16, 8, 4), dim3(256), 0, stream>>>(Qh, Kh, Vt, Opart, Psum);

    out_gemm<<<dim3(64, 4, 2), dim3(256), 0, stream>>>(
        ow, ob, Opart, Psum, image, out);
}